// Round 11
// baseline (269.017 us; speedup 1.0000x reference)
//
#include <hip/hip_runtime.h>
#include <hip/hip_bf16.h>

// Problem constants
#define NN 16
#define CF 768
#define CC 64
#define HH 56
#define WW 56
#define SS 40
#define PP (SS*SS)          // 1600 positions per image
#define PPAD 1664           // padded to 13*128 for 128-tile GEMM
#define NPT (NN*PP)         // 25600
#define NPTP (NN*PPAD)      // 26624
#define HWP (HH*WW)         // 3136

typedef __attribute__((ext_vector_type(8))) short short8;
typedef __attribute__((ext_vector_type(4))) float f32x4;

typedef const __attribute__((address_space(1))) void* gas_p;
typedef __attribute__((address_space(3))) void* las_p;

// Shared bilinear helper — EXACT same arithmetic as validated round-1 kernel.
__device__ __forceinline__ void bilin(float gx, float gy,
    int& o00, int& o01, int& o10, int& o11,
    float& w00, float& w01, float& w10, float& w11)
{
    float x = (gx + 1.f) * 0.5f * (float)(WW - 1);
    float y = (gy + 1.f) * 0.5f * (float)(HH - 1);
    x = fminf(fmaxf(x, 0.f), (float)(WW - 1));
    y = fminf(fmaxf(y, 0.f), (float)(HH - 1));
    float xf = floorf(x), yf = floorf(y);
    int x0 = (int)xf, y0 = (int)yf;
    int x1 = min(x0 + 1, WW - 1), y1 = min(y0 + 1, HH - 1);
    float wx = x - xf, wy = y - yf;
    w00 = (1.f-wx)*(1.f-wy); w01 = wx*(1.f-wy); w10 = (1.f-wx)*wy; w11 = wx*wy;
    o00 = y0*WW + x0; o01 = y0*WW + x1; o10 = y1*WW + x0; o11 = y1*WW + x1;
}

// ---------------------------------------------------------------------------
// Kernel 1: sampling — VERBATIM round-8/9 (passed 3x): fp8 k-major feats
// [n][24][4][1664][8B], bf16 code [n][2][1664][32 shorts].
// ---------------------------------------------------------------------------
__global__ __launch_bounds__(256) void k_sample(
    const float* __restrict__ f0, const float* __restrict__ f1,
    const float* __restrict__ c0in, const float* __restrict__ c1in,
    const float* __restrict__ g0, const float* __restrict__ g1,
    float* __restrict__ nrmF, float* __restrict__ nrmC,
    unsigned char* __restrict__ OF0, unsigned char* __restrict__ OF1,
    short* __restrict__ OC0, short* __restrict__ OC1)
{
    // decode quarter-interleaved flat index (identical to validated kernel)
    const int flat = blockIdx.x;                       // [0, 3328)
    const int q    = (flat >> 3) & 3;                  // quarter
    const int u    = ((flat >> 5) << 3) | (flat & 7);  // [0, 832)
    const int set  = u / 416;                          // 26*16 = 416
    const int rem  = u % 416;
    const int n    = rem / 26;
    const int v    = rem % 26;                         // 0..23 feats, 24..25 code
    const bool isF = v < 24;
    const int ks   = isF ? v : v - 24;
    const int g    = ks * 4 + q;                       // 8-channel group index

    const float* src0; float* nrm;
    if (isF) {
        src0 = (set ? f1 : f0) + ((size_t)n * CF + g * 8) * HWP;
        nrm  = nrmF + (size_t)set * NPTP;
    } else {
        src0 = (set ? c1in : c0in) + ((size_t)n * CC + g * 8) * HWP;
        nrm  = nrmC + (size_t)set * NPTP;
    }
    unsigned char* outF = set ? OF1 : OF0;
    short*         outC = set ? OC1 : OC0;
    const float* gr = set ? g1 : g0;
    const int t = threadIdx.x;

    __shared__ float plane[2][4096];   // 2 x 16 KB double buffer (784 f4 used)

    // ---- per-position bilinear meta, computed once ----
    int   po[7], pdx[7], pdw[7];
    float pw[7][4];
    #pragma unroll
    for (int i = 0; i < 7; i++) {
        int p = t + i * 256;
        if (p < PP) {
            float2 gg = *(const float2*)&gr[2 * (n * PP + p)];
            int o00, o01, o10, o11; float w00, w01, w10, w11;
            bilin(gg.x*2.f - 1.f, gg.y*2.f - 1.f, o00, o01, o10, o11, w00, w01, w10, w11);
            po[i] = o00; pdx[i] = o01 - o00; pdw[i] = o10 - o00;
            pw[i][0] = w00; pw[i][1] = w01; pw[i][2] = w10; pw[i][3] = w11;
        } else {
            po[i] = 0; pdx[i] = 0; pdw[i] = 0;
            pw[i][0] = pw[i][1] = pw[i][2] = pw[i][3] = 0.f;   // pad -> exact 0
        }
    }

    auto* pl3 = (__attribute__((address_space(3))) char*)&plane[0][0];

#define ISSUE(C)                                                                    \
    do {                                                                            \
        const char* sp_ = (const char*)(src0 + (C) * HWP);                          \
        _Pragma("unroll")                                                           \
        for (int i_ = 0; i_ < 4; i_++) {                                            \
            int j_  = t + i_ * 256;                                                 \
            int jc_ = min(j_, 783);                                                 \
            __builtin_amdgcn_global_load_lds((gas_p)(sp_ + jc_ * 16),               \
                (las_p)(pl3 + (((C) & 1) * 16384 + j_ * 16)), 16, 0, 0);            \
        }                                                                           \
    } while (0)

    float ss[7];
    float fv[7][8];     // per-position channel values (indices all constant)
    #pragma unroll
    for (int i = 0; i < 7; i++) ss[i] = 0.f;

    ISSUE(0);
    #pragma unroll
    for (int c = 0; c < 8; c++) {
        if (c < 7) {
            ISSUE(c + 1);
            asm volatile("s_waitcnt vmcnt(4)" ::: "memory");   // my ch-c loads done
        } else {
            asm volatile("s_waitcnt vmcnt(0)" ::: "memory");
        }
        __builtin_amdgcn_sched_barrier(0);
        __builtin_amdgcn_s_barrier();              // all waves' ch-c loads done
        const float* pl = &plane[c & 1][0];
        #pragma unroll
        for (int i = 0; i < 7; i++) {
            float val = pw[i][0] * pl[po[i]]
                      + pw[i][1] * pl[po[i] + pdx[i]]
                      + pw[i][2] * pl[po[i] + pdw[i]]
                      + pw[i][3] * pl[po[i] + pdw[i] + pdx[i]];
            ss[i] += val * val;
            fv[i][c] = val;
        }
        __builtin_amdgcn_sched_barrier(0);
        __builtin_amdgcn_s_barrier();              // compute done before reuse
    }
#undef ISSUE

    if (isF) {
        // k-major fp8 layout: [n][24][q=4][p][8 B]; this block owns kchunk q
        const size_t ob = ((size_t)((n * 24 + ks) * 4 + q)) * PPAD * 8;
        #pragma unroll
        for (int i = 0; i < 7; i++) {
            int p = t + i * 256;
            if (p < PPAD) {
                unsigned w0 = 0u, w1 = 0u;
                w0 = __builtin_amdgcn_cvt_pk_fp8_f32(fv[i][0], fv[i][1], w0, 0);
                w0 = __builtin_amdgcn_cvt_pk_fp8_f32(fv[i][2], fv[i][3], w0, 1);
                w1 = __builtin_amdgcn_cvt_pk_fp8_f32(fv[i][4], fv[i][5], w1, 0);
                w1 = __builtin_amdgcn_cvt_pk_fp8_f32(fv[i][6], fv[i][7], w1, 1);
                uint2 w; w.x = w0; w.y = w1;
                *(uint2*)&outF[ob + (size_t)p * 8] = w;
                if (p < PP) atomicAdd(&nrm[n * PPAD + p], ss[i]);
            }
        }
    } else {
        // [n][2][p][32 shorts] bf16 layout (unchanged)
        const size_t ob = ((size_t)(n * 2 + ks)) * PPAD * 32 + q * 8;
        #pragma unroll
        for (int i = 0; i < 7; i++) {
            int p = t + i * 256;
            if (p < PPAD) {
                short ov[8] __attribute__((aligned(16)));
                #pragma unroll
                for (int c = 0; c < 8; c++) {
                    __hip_bfloat16 b = __float2bfloat16(fv[i][c]);
                    ov[c] = *(short*)&b;
                }
                *(short8*)&outC[ob + (size_t)p * 32] = *(const short8*)ov;
                if (p < PP) atomicAdd(&nrm[n * PPAD + p], ss[i]);
            }
        }
    }
}

// ---------------------------------------------------------------------------
// Kernel 2: nrm -> scale (validated round 10). Pad rows -> scale 0.
// ---------------------------------------------------------------------------
__global__ __launch_bounds__(256) void k_nrm(
    const float* __restrict__ nrmF, const float* __restrict__ nrmC,
    float* __restrict__ sclF, float* __restrict__ sclC)
{
    const int i = blockIdx.x * 256 + threadIdx.x;    // [0, 2*NPTP)
    if (i >= 2 * NPTP) return;
    const float* nrm = blockIdx.y ? nrmC : nrmF;
    float*       scl = blockIdx.y ? sclC : sclF;
    const int p = i % PPAD;
    float s = (p < PP) ? 1.f / fmaxf(sqrtf(nrm[i]), 1e-10f) : 0.f;
    scl[i] = s;
}

// ---------------------------------------------------------------------------
// Kernel 3: fused dual correlation GEMM — round 26: round-10's 128x256
// 8-wave fp8-fd structure, with cd REVERTED to the validated bf16 path
// (round-10's marginal absmax fail 5.96e-8 was cd-fp8 quantization; fd-fp8
// passed 3x at 2.98e-8). cd bf16 slabs staged into the freed buffers after
// the fd loop (old XOR-swizzle geometry widened to 512 thr), computed per-m
// in the epilogue with a transient 16-reg accumulator.
// Staged bytes 606 -> 489 MB. LDS 72KB -> 2 blocks/CU = 16 waves/CU.
// ---------------------------------------------------------------------------
__global__ __launch_bounds__(512, 4) void k_corr(
    const unsigned char* __restrict__ A, const unsigned char* __restrict__ B,
    const short* __restrict__ C, const short* __restrict__ D,
    const float* __restrict__ sF, const float* __restrict__ sC,
    float* __restrict__ rowfd, float* __restrict__ rowrc, float* __restrict__ t1out)
{
    // XCD-chunked swizzle: 1456 blocks = 8 XCDs x 182 (bijective)
    const int flat = blockIdx.x;
    const int v   = (flat & 7) * 182 + (flat >> 3);
    const int n   = v / 91;                 // 13 M-tiles x 7 N-tiles per n
    const int rr  = v - n * 91;
    const int bp1 = (rr / 7) * 128;         // M tile base (exact: 13*128=1664)
    const int bp2 = (rr % 7) * 256;         // N tile base (overhang clamped)

    __shared__ char Asb[3][8192];    // fd: [buf][8 kchunk][128 row][8B]; cd: slabs
    __shared__ char Bsb[3][16384];   // fd: [buf][8 kchunk][256 row][8B]; cd: slabs
    __shared__ float t1s[8];

    const int t    = threadIdx.x;
    const int wv   = t >> 6, lane = t & 63;
    const int wm   = wv >> 2, wn = wv & 3;           // 2 M-halves x 4 N-quads
    const int frow = lane & 15, fcg = lane >> 4;     // fragment row / k-chunk
    const int fslot = fcg ^ ((frow >> 1) & 3);       // bank-swizzled slot (cd bf16)

    // ---- fd (fp8) staging geometry, k-major, BK=64 (r10 verbatim) ----
    const size_t FDTILE = (size_t)PPAD * 64;         // BYTES per fp8 BK=64 tile
    const unsigned char* fdA = A + (size_t)n * 24 * ((size_t)PPAD * 32);
    const unsigned char* fdB = B + (size_t)n * 24 * ((size_t)PPAD * 32);
    const size_t toAf  = (size_t)wv * (PPAD * 8) + (size_t)(bp1 + 2 * lane) * 8;
    const int rB0 = min(bp2 +       2 * lane, PPAD - 2);   // pad rows zero
    const int rB1 = min(bp2 + 128 + 2 * lane, PPAD - 2);
    const size_t toBf0 = (size_t)wv * (PPAD * 8) + (size_t)rB0 * 8;
    const size_t toBf1 = (size_t)wv * (PPAD * 8) + (size_t)rB1 * 8;
    auto* Asb3 = (__attribute__((address_space(3))) char*)&Asb[0][0];
    auto* Bsb3 = (__attribute__((address_space(3))) char*)&Bsb[0][0];
    const int ldsA  = wv * 1024;          // wave-uniform byte base (+lane*16)
    const int ldsB0 = wv * 2048;
    const int ldsB1 = wv * 2048 + 1024;

    // ---- cd (bf16) staging geometry: old validated XOR-swizzle, 512 thr ----
    const short* cdC = C + (size_t)n * 2 * ((size_t)PPAD * 32);
    const short* cdD = D + (size_t)n * 2 * ((size_t)PPAD * 32);
    const int gA   = wv * 64 + lane;                 // [0,512): A chunks
    const int rowA = gA >> 2;
    const int cgA  = (gA & 3) ^ ((rowA >> 1) & 3);
    const size_t toAc = (size_t)(bp1 + rowA) * 32 + cgA * 8;       // shorts
    const int gB0  = wv * 128 + lane, gB1 = gB0 + 64;   // [0,1024): B chunks
    const int rowB0 = gB0 >> 2, rowB1 = gB1 >> 2;
    const int cgB0 = (gB0 & 3) ^ ((rowB0 >> 1) & 3);
    const int cgB1 = (gB1 & 3) ^ ((rowB1 >> 1) & 3);
    const size_t toBc0 = (size_t)min(bp2 + rowB0, PPAD - 1) * 32 + cgB0 * 8;
    const size_t toBc1 = (size_t)min(bp2 + rowB1, PPAD - 1) * 32 + cgB1 * 8;
    auto* As3s = (__attribute__((address_space(3))) short*)&Asb[0][0];
    auto* Bs3s = (__attribute__((address_space(3))) short*)&Bsb[0][0];
    const int ldsAc  = wv * 512;                     // shorts (wave-uniform)
    const int ldsBc0 = wv * 1024;
    const int ldsBc1 = wv * 1024 + 512;

// stage one BK=64 fp8 fd tile (A 8KB + B 16KB) into buffer BUF: 3 glds
#define STAGEF(TILE, BUF)                                                           \
    do {                                                                            \
        const size_t off_ = (size_t)(TILE) * FDTILE;                                \
        __builtin_amdgcn_global_load_lds((gas_p)(fdA + toAf + off_),                \
            (las_p)(Asb3 + (BUF) * 8192 + ldsA), 16, 0, 0);                         \
        __builtin_amdgcn_global_load_lds((gas_p)(fdB + toBf0 + off_),               \
            (las_p)(Bsb3 + (BUF) * 16384 + ldsB0), 16, 0, 0);                       \
        __builtin_amdgcn_global_load_lds((gas_p)(fdB + toBf1 + off_),               \
            (las_p)(Bsb3 + (BUF) * 16384 + ldsB1), 16, 0, 0);                       \
    } while (0)

// stage one cd bf16 slab (A 8KB -> Asb[KS], B 16KB -> Bsb[KS]): 3 glds
#define STAGECD(KS)                                                                 \
    do {                                                                            \
        const size_t o_ = (size_t)(KS) * ((size_t)PPAD * 32);                       \
        __builtin_amdgcn_global_load_lds((gas_p)(cdC + toAc + o_),                  \
            (las_p)(As3s + (KS) * 4096 + ldsAc), 16, 0, 0);                         \
        __builtin_amdgcn_global_load_lds((gas_p)(cdD + toBc0 + o_),                 \
            (las_p)(Bs3s + (KS) * 8192 + ldsBc0), 16, 0, 0);                        \
        __builtin_amdgcn_global_load_lds((gas_p)(cdD + toBc1 + o_),                 \
            (las_p)(Bs3s + (KS) * 8192 + ldsBc1), 16, 0, 0);                        \
    } while (0)

// BK=64 fp8 compute: 2 K-substeps; LDS kchunk = kk*4 + fcg; quarter-wave
// reads 16 consecutive 8B granules (all 32 banks once) — conflict-free.
#define COMPUTEF64(BUF, ACC)                                                        \
    do {                                                                            \
        _Pragma("unroll")                                                           \
        for (int kk_ = 0; kk_ < 2; kk_++) {                                         \
            const int ka_ = (BUF) * 8192  + (kk_ * 4 + fcg) * 1024;                 \
            const int kb_ = (BUF) * 16384 + (kk_ * 4 + fcg) * 2048;                 \
            long af[4], bf[4];                                                      \
            _Pragma("unroll")                                                       \
            for (int m = 0; m < 4; m++)                                             \
                af[m] = *(const long*)&Asb[0][ka_ + (wm*64 + m*16 + frow)*8];       \
            _Pragma("unroll")                                                       \
            for (int q = 0; q < 4; q++)                                             \
                bf[q] = *(const long*)&Bsb[0][kb_ + (wn*64 + q*16 + frow)*8];       \
            _Pragma("unroll")                                                       \
            for (int m = 0; m < 4; m++)                                             \
                _Pragma("unroll")                                                   \
                for (int q = 0; q < 4; q++)                                         \
                    ACC[m][q] = __builtin_amdgcn_mfma_f32_16x16x32_fp8_fp8(af[m], bf[q], ACC[m][q], 0, 0, 0); \
        }                                                                           \
    } while (0)

#define WAITV3  do { asm volatile("s_waitcnt vmcnt(3)" ::: "memory");               \
                     __builtin_amdgcn_sched_barrier(0);                             \
                     __builtin_amdgcn_s_barrier(); } while (0)
#define WAITV0  do { asm volatile("s_waitcnt vmcnt(0)" ::: "memory");               \
                     __builtin_amdgcn_sched_barrier(0);                             \
                     __builtin_amdgcn_s_barrier(); } while (0)

    // ---- fd main loop: 12 BK=64 tiles, tile j -> buf j%3, stage 2-ahead ----
    f32x4 accfd[4][4];
    #pragma unroll
    for (int m = 0; m < 4; m++)
        #pragma unroll
        for (int q = 0; q < 4; q++)
            #pragma unroll
            for (int r = 0; r < 4; r++) accfd[m][q][r] = 0.f;

    STAGEF(0, 0);
    STAGEF(1, 1);

    for (int kp = 0; kp < 4; kp++) {
        const int tb = 3 * kp;
        // slot: compute tile 3kp (buf0), stage tile 3kp+2 -> buf2
        WAITV3;
        STAGEF(tb + 2, 2);
        COMPUTEF64(0, accfd);
        // slot: compute tile 3kp+1 (buf1), stage tile 3kp+3 -> buf0
        WAITV3;
        if (kp < 3) STAGEF(tb + 3, 0);
        COMPUTEF64(1, accfd);
        // slot: compute tile 3kp+2 (buf2), stage tile 3kp+4 -> buf1
        if (kp < 3) {
            WAITV3;
            STAGEF(tb + 4, 1);
        } else {
            WAITV0;
        }
        COMPUTEF64(2, accfd);
    }

    // ---- stage cd bf16 slabs into freed buffers 0,1; drain; epilogue ----
    // (all fd reads done: last barrier was WAITV0; COMPUTEF64(2) reads buf2)
    STAGECD(0);
    STAGECD(1);
    asm volatile("s_waitcnt vmcnt(0)" ::: "memory");
    __builtin_amdgcn_sched_barrier(0);
    __builtin_amdgcn_s_barrier();
#undef STAGEF
#undef STAGECD
#undef COMPUTEF64
#undef WAITV3
#undef WAITV0

    // ---- epilogue: per-m cd GEMM (bf16, transient acc) + scales + sums ----
    // C/D layout: col = lane&15, row = (lane>>4)*4 + reg (dtype-independent)
    const short* AsS = (const short*)&Asb[0][0];
    const short* BsS = (const short*)&Bsb[0][0];

    float scc_[4], sfc_[4];
    #pragma unroll
    for (int q = 0; q < 4; q++) {
        int c = min(bp2 + wn*64 + q*16 + frow, PPAD - 1);   // pad cols -> scale 0
        size_t colp = (size_t)NPTP + (size_t)n * PPAD + c;
        scc_[q] = sC[colp];
        sfc_[q] = sF[colp];
    }

    float t1 = 0.f;
    #pragma unroll
    for (int m = 0; m < 4; m++) {
        f32x4 a2[4];
        #pragma unroll
        for (int q = 0; q < 4; q++)
            #pragma unroll
            for (int r = 0; r < 4; r++) a2[q][r] = 0.f;
        short8 ac0 = *(const short8*)&AsS[0*4096 + (wm*64 + m*16 + frow)*32 + fslot*8];
        short8 ac1 = *(const short8*)&AsS[1*4096 + (wm*64 + m*16 + frow)*32 + fslot*8];
        #pragma unroll
        for (int q = 0; q < 4; q++) {
            short8 bc0 = *(const short8*)&BsS[0*8192 + (wn*64 + q*16 + frow)*32 + fslot*8];
            short8 bc1 = *(const short8*)&BsS[1*8192 + (wn*64 + q*16 + frow)*32 + fslot*8];
            a2[q] = __builtin_amdgcn_mfma_f32_16x16x32_bf16(ac0, bc0, a2[q], 0, 0, 0);
            a2[q] = __builtin_amdgcn_mfma_f32_16x16x32_bf16(ac1, bc1, a2[q], 0, 0, 0);
        }
        #pragma unroll
        for (int r = 0; r < 4; r++) {
            size_t rowp = (size_t)n * PPAD + bp1 + wm*64 + m*16 + fcg*4 + r;
            float scr = sC[rowp];
            float sfr = sF[rowp];
            float sf = 0.f, sr = 0.f;
            #pragma unroll
            for (int q = 0; q < 4; q++) {
                float fdv = accfd[m][q][r] * sfr * sfc_[q];
                float rcv = fmaxf(a2[q][r], 0.f) * scr * scc_[q];
                t1 += rcv * fdv;
                sf += fdv;
                sr += rcv;
            }
            #pragma unroll
            for (int d = 1; d < 16; d <<= 1) {
                sf += __shfl_xor(sf, d, 64);
                sr += __shfl_xor(sr, d, 64);
            }
            if ((lane & 15) == 0) {
                int row = bp1 + wm*64 + m*16 + fcg*4 + r;
                atomicAdd(&rowfd[n * PPAD + row], sf);
                atomicAdd(&rowrc[n * PPAD + row], sr);
            }
        }
    }
    #pragma unroll
    for (int d = 1; d < 64; d <<= 1) t1 += __shfl_xor(t1, d, 64);
    if (lane == 0) t1s[wv] = t1;
    __syncthreads();
    if (t == 0) {
        float s = 0.f;
        #pragma unroll
        for (int w = 0; w < 8; w++) s += t1s[w];
        atomicAdd(t1out, s);
    }
}

// ---------------------------------------------------------------------------
// Kernel 4: finalize. loss = -(T1 - cross/PP + (Sfd/M)*Src)/M
// ---------------------------------------------------------------------------
__global__ __launch_bounds__(1024) void k_final(
    const float* __restrict__ rowfd, const float* __restrict__ rowrc,
    const float* __restrict__ t1p, float* __restrict__ out)
{
    const int t = threadIdx.x;
    double cr = 0.0, sf = 0.0, sr = 0.0;
    for (int i = t; i < NN * PPAD; i += 1024) {
        double a = rowfd[i], b = rowrc[i];
        cr += a * b; sf += a; sr += b;
    }
    __shared__ double sh[1024];
    sh[t] = cr; __syncthreads();
    for (int s = 512; s > 0; s >>= 1) { if (t < s) sh[t] += sh[t + s]; __syncthreads(); }
    cr = sh[0]; __syncthreads();
    sh[t] = sf; __syncthreads();
    for (int s = 512; s > 0; s >>= 1) { if (t < s) sh[t] += sh[t + s]; __syncthreads(); }
    sf = sh[0]; __syncthreads();
    sh[t] = sr; __syncthreads();
    for (int s = 512; s > 0; s >>= 1) { if (t < s) sh[t] += sh[t + s]; __syncthreads(); }
    sr = sh[0];
    if (t == 0) {
        double M = (double)NN * (double)PP * (double)PP;
        double t1 = (double)t1p[0];
        double bracket = t1 - cr / (double)PP + (sf / M) * sr;
        out[0] = (float)(-bracket / M);
    }
}

// ---------------------------------------------------------------------------
extern "C" void kernel_launch(void* const* d_in, const int* in_sizes, int n_in,
                              void* d_out, int out_size, void* d_ws, size_t ws_size,
                              hipStream_t stream)
{
    const float* orig_feats     = (const float*)d_in[0];
    const float* orig_feats_pos = (const float*)d_in[1];
    const float* orig_code      = (const float*)d_in[2];
    const float* orig_code_pos  = (const float*)d_in[3];
    const float* coords1        = (const float*)d_in[4];
    const float* coords2        = (const float*)d_in[5];

    // ---- workspace layout ----
    char* ws = (char*)d_ws;
    float* t1    = (float*)(ws + 0);                      //      256 B
    float* rowfd = (float*)(ws + 256);                    //  106,496 B (NN*PPAD)
    float* rowrc = (float*)(ws + 106752);                 //  106,496 B
    float* nrmF  = (float*)(ws + 213248);                 //  212,992 B (2*NPTP)
    float* nrmC  = (float*)(ws + 426240);                 //  212,992 B
    const size_t zeroBytes = 639232;                      // t1+rowsums+nrms
    float* sclF  = (float*)(ws + 639232);                 //  212,992 B
    float* sclC  = (float*)(ws + 852224);                 //  212,992 B
    unsigned char* OF0 = (unsigned char*)(ws + 1065216);  // [16][24][4][1664][8B] fp8
    unsigned char* OF1 = OF0 + 20447232ull;
    short* OC0 = (short*)(OF1 + 20447232ull);             // [16][2][1664][32] bf16
    short* OC1 = (short*)((char*)OC0 + 3407872ull);

    (void)hipMemsetAsync(d_ws, 0, zeroBytes, stream);   // t1/rowsums/nrms

    k_sample<<<dim3(3328), 256, 0, stream>>>(
        orig_feats, orig_feats_pos, orig_code, orig_code_pos,
        coords1, coords2, nrmF, nrmC, OF0, OF1, OC0, OC1);

    k_nrm<<<dim3((2*NPTP + 255)/256, 2), 256, 0, stream>>>(
        nrmF, nrmC, sclF, sclC);

    k_corr<<<dim3(1456), 512, 0, stream>>>(
        OF0, OF1, OC0, OC1, sclF, sclC, rowfd, rowrc, t1);

    k_final<<<1, 1024, 0, stream>>>(rowfd, rowrc, t1, (float*)d_out);
}

// Round 12
// 211.481 us; speedup vs baseline: 1.2721x; 1.2721x over previous
//
#include <hip/hip_runtime.h>
#include <hip/hip_bf16.h>

// Problem constants
#define NN 16
#define CF 768
#define CC 64
#define HH 56
#define WW 56
#define SS 40
#define PP (SS*SS)          // 1600 positions per image
#define PPAD 1664           // padded to 13*128 for 128-tile GEMM
#define NPT (NN*PP)         // 25600
#define NPTP (NN*PPAD)      // 26624
#define HWP (HH*WW)         // 3136

typedef __attribute__((ext_vector_type(8))) short short8;
typedef __attribute__((ext_vector_type(4))) float f32x4;

typedef const __attribute__((address_space(1))) void* gas_p;
typedef __attribute__((address_space(3))) void* las_p;

__device__ __forceinline__ unsigned f2b(float f) {
    __hip_bfloat16 b = __float2bfloat16(f);
    return (unsigned)*(unsigned short*)&b;
}
__device__ __forceinline__ float bup(unsigned u, int hi) {
    unsigned bits = hi ? (u & 0xffff0000u) : (u << 16);
    return __uint_as_float(bits);
}

// Shared bilinear helper — EXACT same arithmetic as validated round-1 kernel.
__device__ __forceinline__ void bilin(float gx, float gy,
    int& o00, int& o01, int& o10, int& o11,
    float& w00, float& w01, float& w10, float& w11)
{
    float x = (gx + 1.f) * 0.5f * (float)(WW - 1);
    float y = (gy + 1.f) * 0.5f * (float)(HH - 1);
    x = fminf(fmaxf(x, 0.f), (float)(WW - 1));
    y = fminf(fmaxf(y, 0.f), (float)(HH - 1));
    float xf = floorf(x), yf = floorf(y);
    int x0 = (int)xf, y0 = (int)yf;
    int x1 = min(x0 + 1, WW - 1), y1 = min(y0 + 1, HH - 1);
    float wx = x - xf, wy = y - yf;
    w00 = (1.f-wx)*(1.f-wy); w01 = wx*(1.f-wy); w10 = (1.f-wx)*wy; w11 = wx*wy;
    o00 = y0*WW + x0; o01 = y0*WW + x1; o10 = y1*WW + x0; o11 = y1*WW + x1;
}

// ---------------------------------------------------------------------------
// Kernel 1: sampling — VERBATIM round-8/9 (validated, passed 3x): fp8 k-major
// feats [n][24][4][1664][8B], bf16 code [n][2][1664][32 shorts].
// ---------------------------------------------------------------------------
__global__ __launch_bounds__(256) void k_sample(
    const float* __restrict__ f0, const float* __restrict__ f1,
    const float* __restrict__ c0in, const float* __restrict__ c1in,
    const float* __restrict__ g0, const float* __restrict__ g1,
    float* __restrict__ nrmF, float* __restrict__ nrmC,
    unsigned char* __restrict__ OF0, unsigned char* __restrict__ OF1,
    short* __restrict__ OC0, short* __restrict__ OC1)
{
    // decode quarter-interleaved flat index (identical to validated kernel)
    const int flat = blockIdx.x;                       // [0, 3328)
    const int q    = (flat >> 3) & 3;                  // quarter
    const int u    = ((flat >> 5) << 3) | (flat & 7);  // [0, 832)
    const int set  = u / 416;                          // 26*16 = 416
    const int rem  = u % 416;
    const int n    = rem / 26;
    const int v    = rem % 26;                         // 0..23 feats, 24..25 code
    const bool isF = v < 24;
    const int ks   = isF ? v : v - 24;
    const int g    = ks * 4 + q;                       // 8-channel group index

    const float* src0; float* nrm;
    if (isF) {
        src0 = (set ? f1 : f0) + ((size_t)n * CF + g * 8) * HWP;
        nrm  = nrmF + (size_t)set * NPTP;
    } else {
        src0 = (set ? c1in : c0in) + ((size_t)n * CC + g * 8) * HWP;
        nrm  = nrmC + (size_t)set * NPTP;
    }
    unsigned char* outF = set ? OF1 : OF0;
    short*         outC = set ? OC1 : OC0;
    const float* gr = set ? g1 : g0;
    const int t = threadIdx.x;

    __shared__ float plane[2][4096];   // 2 x 16 KB double buffer (784 f4 used)

    // ---- per-position bilinear meta, computed once ----
    int   po[7], pdx[7], pdw[7];
    float pw[7][4];
    #pragma unroll
    for (int i = 0; i < 7; i++) {
        int p = t + i * 256;
        if (p < PP) {
            float2 gg = *(const float2*)&gr[2 * (n * PP + p)];
            int o00, o01, o10, o11; float w00, w01, w10, w11;
            bilin(gg.x*2.f - 1.f, gg.y*2.f - 1.f, o00, o01, o10, o11, w00, w01, w10, w11);
            po[i] = o00; pdx[i] = o01 - o00; pdw[i] = o10 - o00;
            pw[i][0] = w00; pw[i][1] = w01; pw[i][2] = w10; pw[i][3] = w11;
        } else {
            po[i] = 0; pdx[i] = 0; pdw[i] = 0;
            pw[i][0] = pw[i][1] = pw[i][2] = pw[i][3] = 0.f;   // pad -> exact 0
        }
    }

    auto* pl3 = (__attribute__((address_space(3))) char*)&plane[0][0];

#define ISSUE(C)                                                                    \
    do {                                                                            \
        const char* sp_ = (const char*)(src0 + (C) * HWP);                          \
        _Pragma("unroll")                                                           \
        for (int i_ = 0; i_ < 4; i_++) {                                            \
            int j_  = t + i_ * 256;                                                 \
            int jc_ = min(j_, 783);                                                 \
            __builtin_amdgcn_global_load_lds((gas_p)(sp_ + jc_ * 16),               \
                (las_p)(pl3 + (((C) & 1) * 16384 + j_ * 16)), 16, 0, 0);            \
        }                                                                           \
    } while (0)

    float ss[7];
    float fv[7][8];     // per-position channel values (indices all constant)
    #pragma unroll
    for (int i = 0; i < 7; i++) ss[i] = 0.f;

    ISSUE(0);
    #pragma unroll
    for (int c = 0; c < 8; c++) {
        if (c < 7) {
            ISSUE(c + 1);
            asm volatile("s_waitcnt vmcnt(4)" ::: "memory");   // my ch-c loads done
        } else {
            asm volatile("s_waitcnt vmcnt(0)" ::: "memory");
        }
        __builtin_amdgcn_sched_barrier(0);
        __builtin_amdgcn_s_barrier();              // all waves' ch-c loads done
        const float* pl = &plane[c & 1][0];
        #pragma unroll
        for (int i = 0; i < 7; i++) {
            float val = pw[i][0] * pl[po[i]]
                      + pw[i][1] * pl[po[i] + pdx[i]]
                      + pw[i][2] * pl[po[i] + pdw[i]]
                      + pw[i][3] * pl[po[i] + pdw[i] + pdx[i]];
            ss[i] += val * val;
            fv[i][c] = val;
        }
        __builtin_amdgcn_sched_barrier(0);
        __builtin_amdgcn_s_barrier();              // compute done before reuse
    }
#undef ISSUE

    if (isF) {
        // k-major fp8 layout: [n][24][q=4][p][8 B]; this block owns kchunk q
        const size_t ob = ((size_t)((n * 24 + ks) * 4 + q)) * PPAD * 8;
        #pragma unroll
        for (int i = 0; i < 7; i++) {
            int p = t + i * 256;
            if (p < PPAD) {
                unsigned w0 = 0u, w1 = 0u;
                w0 = __builtin_amdgcn_cvt_pk_fp8_f32(fv[i][0], fv[i][1], w0, 0);
                w0 = __builtin_amdgcn_cvt_pk_fp8_f32(fv[i][2], fv[i][3], w0, 1);
                w1 = __builtin_amdgcn_cvt_pk_fp8_f32(fv[i][4], fv[i][5], w1, 0);
                w1 = __builtin_amdgcn_cvt_pk_fp8_f32(fv[i][6], fv[i][7], w1, 1);
                uint2 w; w.x = w0; w.y = w1;
                *(uint2*)&outF[ob + (size_t)p * 8] = w;
                if (p < PP) atomicAdd(&nrm[n * PPAD + p], ss[i]);
            }
        }
    } else {
        // [n][2][p][32 shorts] bf16 layout (unchanged)
        const size_t ob = ((size_t)(n * 2 + ks)) * PPAD * 32 + q * 8;
        #pragma unroll
        for (int i = 0; i < 7; i++) {
            int p = t + i * 256;
            if (p < PPAD) {
                short ov[8] __attribute__((aligned(16)));
                #pragma unroll
                for (int c = 0; c < 8; c++) {
                    __hip_bfloat16 b = __float2bfloat16(fv[i][c]);
                    ov[c] = *(short*)&b;
                }
                *(short8*)&outC[ob + (size_t)p * 32] = *(const short8*)ov;
                if (p < PP) atomicAdd(&nrm[n * PPAD + p], ss[i]);
            }
        }
    }
}

// ---------------------------------------------------------------------------
// Kernel 2: nrm -> scale (validated round 10). Pad rows -> scale 0.
// ---------------------------------------------------------------------------
__global__ __launch_bounds__(256) void k_nrm(
    const float* __restrict__ nrmF, const float* __restrict__ nrmC,
    float* __restrict__ sclF, float* __restrict__ sclC)
{
    const int i = blockIdx.x * 256 + threadIdx.x;    // [0, 2*NPTP)
    if (i >= 2 * NPTP) return;
    const float* nrm = blockIdx.y ? nrmC : nrmF;
    float*       scl = blockIdx.y ? sclC : sclF;
    const int p = i % PPAD;
    float s = (p < PP) ? 1.f / fmaxf(sqrtf(nrm[i]), 1e-10f) : 0.f;
    scl[i] = s;
}

// ---------------------------------------------------------------------------
// Kernel 3: fused dual correlation GEMM — VERBATIM round-9 (validated best,
// k_corr ~122us): fp8 k-major fd with BK=64 slots (12 fd + 2 cd), 3-buffer
// counted-vmcnt pipeline, conflict-free k-major LDS reads, bf16 cd prologue
// with deferred pcd pack, XCD-chunked swizzle, 84 VGPR / 3 blocks/CU.
// Five tile-growth attempts (r1/r2/r3/r10/r11) all hit the register wall;
// this 128x128/4-wave geometry is the register-feasible optimum.
// ---------------------------------------------------------------------------
__global__ __launch_bounds__(256, 3) void k_corr(
    const unsigned char* __restrict__ A, const unsigned char* __restrict__ B,
    const short* __restrict__ C, const short* __restrict__ D,
    const float* __restrict__ sF, const float* __restrict__ sC,
    float* __restrict__ rowfd, float* __restrict__ rowrc, float* __restrict__ t1out)
{
    // XCD-chunked swizzle: 2704 blocks = 8 XCDs x 338; x fastest within chunk
    const int flat = blockIdx.x;
    const int v   = (flat & 7) * 338 + (flat >> 3);
    const int n   = v / 169;
    const int rr  = v - n * 169;
    const int bp1 = (rr / 13) * 128;
    const int bp2 = (rr % 13) * 128;

    __shared__ char Asb[3][8192];   // 3 buffers x 8 KB (cd bf16 slab / fd fp8 BK=64 tile)
    __shared__ char Bsb[3][8192];

    const int t    = threadIdx.x;
    const int wv   = t >> 6, lane = t & 63;
    const int wm   = wv >> 1, wn = wv & 1;
    const int frow = lane & 15, fcg = lane >> 4;     // fragment row / k-chunk
    const int fslot = fcg ^ ((frow >> 1) & 3);       // bank-swizzled slot (cd bf16)

    // ---- cd (bf16) staging geometry: chunk g = (wv*2+i)*64 + lane, [0,512)
    const int sg0  = wv * 2 * 64 + lane;
    const int row0 = sg0 >> 2,        cg0 = (sg0 & 3) ^ ((row0 >> 1) & 3);
    const int sg1  = sg0 + 64;
    const int row1 = sg1 >> 2,        cg1 = (sg1 & 3) ^ ((row1 >> 1) & 3);
    const size_t kstep_s = (size_t)PPAD * 32;        // shorts per bf16 BK=32 slab
    const short* cdC = C + (size_t)n * 2 * kstep_s;
    const short* cdD = D + (size_t)n * 2 * kstep_s;
    const size_t toA0 = (size_t)(bp1 + row0) * 32 + cg0 * 8;
    const size_t toA1 = (size_t)(bp1 + row1) * 32 + cg1 * 8;
    const size_t toB0 = (size_t)(bp2 + row0) * 32 + cg0 * 8;
    const size_t toB1 = (size_t)(bp2 + row1) * 32 + cg1 * 8;
    auto* As3s = (__attribute__((address_space(3))) short*)&Asb[0][0];
    auto* Bs3s = (__attribute__((address_space(3))) short*)&Bsb[0][0];
    const short* AsS = (const short*)&Asb[0][0];
    const short* BsS = (const short*)&Bsb[0][0];
    const int ldsA0 = (wv * 2    ) * 512;  // shorts within one 4096-short buffer
    const int ldsA1 = (wv * 2 + 1) * 512;

    // ---- fd (fp8) staging geometry, k-major, BK=64 ----
    // global: [n][24 steps][4][PPAD][8B] = linear kchunks 0..95, kchunk K at
    // byte K*(PPAD*8). BK=64 tile T = kchunks 8T..8T+7, FDTILE bytes apart.
    const size_t FDTILE = (size_t)PPAD * 64;         // BYTES per fp8 BK=64 tile
    const unsigned char* fdA = A + (size_t)n * 24 * ((size_t)PPAD * 32);
    const unsigned char* fdB = B + (size_t)n * 24 * ((size_t)PPAD * 32);
    // wave wv, glds j in {0,1}: fills LDS kchunk (wv*2+j); lane covers rows
    // 2*lane, 2*lane+1 (16B). Global src = kchunk byte base + (bp+2*lane)*8.
    const size_t toAf0 = (size_t)(wv * 2    ) * (PPAD * 8) + (size_t)(bp1 + 2 * lane) * 8;
    const size_t toAf1 = (size_t)(wv * 2 + 1) * (PPAD * 8) + (size_t)(bp1 + 2 * lane) * 8;
    const size_t toBf0 = (size_t)(wv * 2    ) * (PPAD * 8) + (size_t)(bp2 + 2 * lane) * 8;
    const size_t toBf1 = (size_t)(wv * 2 + 1) * (PPAD * 8) + (size_t)(bp2 + 2 * lane) * 8;
    auto* Asb3 = (__attribute__((address_space(3))) char*)&Asb[0][0];
    auto* Bsb3 = (__attribute__((address_space(3))) char*)&Bsb[0][0];
    const int fldsW0 = (wv * 2    ) * 1024;   // wave-uniform byte base (+lane*16)
    const int fldsW1 = (wv * 2 + 1) * 1024;

#define STAGECD(BUF, OFF)                                                           \
    do {                                                                            \
        const size_t off_ = (OFF);                                                  \
        const int b_ = (BUF) * 4096;                                                \
        __builtin_amdgcn_global_load_lds((gas_p)(cdC + toA0 + off_),                \
                                         (las_p)(As3s + b_ + ldsA0), 16, 0, 0);     \
        __builtin_amdgcn_global_load_lds((gas_p)(cdC + toA1 + off_),                \
                                         (las_p)(As3s + b_ + ldsA1), 16, 0, 0);     \
        __builtin_amdgcn_global_load_lds((gas_p)(cdD + toB0 + off_),                \
                                         (las_p)(Bs3s + b_ + ldsA0), 16, 0, 0);     \
        __builtin_amdgcn_global_load_lds((gas_p)(cdD + toB1 + off_),                \
                                         (las_p)(Bs3s + b_ + ldsA1), 16, 0, 0);     \
    } while (0)

// stage one BK=64 fp8 tile (8 KB/operand) into buffer BUF: 4 glds/thread
#define STAGEF(TILE, BUF)                                                           \
    do {                                                                            \
        const size_t off_ = (size_t)(TILE) * FDTILE;                                \
        __builtin_amdgcn_global_load_lds((gas_p)(fdA + toAf0 + off_),               \
                                         (las_p)(Asb3 + (BUF) * 8192 + fldsW0), 16, 0, 0); \
        __builtin_amdgcn_global_load_lds((gas_p)(fdA + toAf1 + off_),               \
                                         (las_p)(Asb3 + (BUF) * 8192 + fldsW1), 16, 0, 0); \
        __builtin_amdgcn_global_load_lds((gas_p)(fdB + toBf0 + off_),               \
                                         (las_p)(Bsb3 + (BUF) * 8192 + fldsW0), 16, 0, 0); \
        __builtin_amdgcn_global_load_lds((gas_p)(fdB + toBf1 + off_),               \
                                         (las_p)(Bsb3 + (BUF) * 8192 + fldsW1), 16, 0, 0); \
    } while (0)

#define COMPUTECD(BUF, ACC)                                                         \
    do {                                                                            \
        short8 af[4], bf[4];                                                        \
        _Pragma("unroll")                                                           \
        for (int m = 0; m < 4; m++)                                                 \
            af[m] = *(const short8*)&AsS[(BUF)*4096 + (wm*64 + m*16 + frow)*32 + fslot*8]; \
        _Pragma("unroll")                                                           \
        for (int q = 0; q < 4; q++)                                                 \
            bf[q] = *(const short8*)&BsS[(BUF)*4096 + (wn*64 + q*16 + frow)*32 + fslot*8]; \
        _Pragma("unroll")                                                           \
        for (int m = 0; m < 4; m++)                                                 \
            _Pragma("unroll")                                                       \
            for (int q = 0; q < 4; q++)                                             \
                ACC[m][q] = __builtin_amdgcn_mfma_f32_16x16x32_bf16(af[m], bf[q], ACC[m][q], 0, 0, 0); \
    } while (0)

// BK=64 fp8 compute: 2 K-substeps; LDS kchunk = kk*4 + fcg; quarter-wave
// reads 16 consecutive 8B granules (all 32 banks once) — conflict-free.
#define COMPUTEF64(BUF, ACC)                                                        \
    do {                                                                            \
        _Pragma("unroll")                                                           \
        for (int kk_ = 0; kk_ < 2; kk_++) {                                         \
            long af[4], bf[4];                                                      \
            const int kb_ = (BUF) * 8192 + (kk_ * 4 + fcg) * 1024;                  \
            _Pragma("unroll")                                                       \
            for (int m = 0; m < 4; m++)                                             \
                af[m] = *(const long*)&Asb[0][kb_ + (wm*64 + m*16 + frow)*8];       \
            _Pragma("unroll")                                                       \
            for (int q = 0; q < 4; q++)                                             \
                bf[q] = *(const long*)&Bsb[0][kb_ + (wn*64 + q*16 + frow)*8];       \
            _Pragma("unroll")                                                       \
            for (int m = 0; m < 4; m++)                                             \
                _Pragma("unroll")                                                   \
                for (int q = 0; q < 4; q++)                                         \
                    ACC[m][q] = __builtin_amdgcn_mfma_f32_16x16x32_fp8_fp8(af[m], bf[q], ACC[m][q], 0, 0, 0); \
        }                                                                           \
    } while (0)

#define WAITV4  do { asm volatile("s_waitcnt vmcnt(4)" ::: "memory");               \
                     __builtin_amdgcn_sched_barrier(0);                             \
                     __builtin_amdgcn_s_barrier(); } while (0)
#define WAITV0  do { asm volatile("s_waitcnt vmcnt(0)" ::: "memory");               \
                     __builtin_amdgcn_sched_barrier(0);                             \
                     __builtin_amdgcn_s_barrier(); } while (0)

    unsigned pcd[4][4][2];   // raw relu(cd) packed as bf16 pairs (32 VGPR)

    // ---- prologue: stage cd steps 0,1 (4 glds each) ----
    STAGECD(0, 0);
    STAGECD(1, kstep_s);

    // ---- cd slots 0,1 ----
    {
        f32x4 acccd[4][4];
        #pragma unroll
        for (int m = 0; m < 4; m++)
            #pragma unroll
            for (int q = 0; q < 4; q++)
                #pragma unroll
                for (int r = 0; r < 4; r++) acccd[m][q][r] = 0.f;

        WAITV4;                         // cd0 landed (cd1's 4 in flight)
        STAGEF(0, 2);                   // fd tile 0 -> buf2 (+4)
        COMPUTECD(0, acccd);
        WAITV4;                         // cd1 landed (fd0's 4 in flight)
        STAGEF(1, 0);                   // fd tile 1 -> buf0 (+4)
        COMPUTECD(1, acccd);

        // pack raw relu(cd) -> bf16 pairs (pure VALU; scales deferred)
        #pragma unroll
        for (int m = 0; m < 4; m++)
            #pragma unroll
            for (int q = 0; q < 4; q++) {
                float r0 = fmaxf(acccd[m][q][0], 0.f);
                float r1 = fmaxf(acccd[m][q][1], 0.f);
                float r2 = fmaxf(acccd[m][q][2], 0.f);
                float r3 = fmaxf(acccd[m][q][3], 0.f);
                pcd[m][q][0] = f2b(r0) | (f2b(r1) << 16);
                pcd[m][q][1] = f2b(r2) | (f2b(r3) << 16);
            }
    }   // acccd dies (AGPRs freed before accfd)

    // ---- fd slots: 12 BK=64 tiles, tile j in buf (2+j)%3, stage 2-ahead ----
    f32x4 accfd[4][4];
    #pragma unroll
    for (int m = 0; m < 4; m++)
        #pragma unroll
        for (int q = 0; q < 4; q++)
            #pragma unroll
            for (int r = 0; r < 4; r++) accfd[m][q][r] = 0.f;

    for (int kp = 0; kp < 4; kp++) {
        const int tb = 3 * kp;
        // slot: compute tile 3kp (buf2), stage tile 3kp+2 -> buf1
        WAITV4;
        STAGEF(tb + 2, 1);
        COMPUTEF64(2, accfd);
        // slot: compute tile 3kp+1 (buf0), stage tile 3kp+3 -> buf2
        WAITV4;
        if (kp < 3) STAGEF(tb + 3, 2);
        COMPUTEF64(0, accfd);
        // slot: compute tile 3kp+2 (buf1), stage tile 3kp+4 -> buf0
        if (kp < 3) {
            WAITV4;
            STAGEF(tb + 4, 0);
        } else {
            WAITV0;
        }
        COMPUTEF64(1, accfd);
    }
#undef STAGECD
#undef STAGEF
#undef COMPUTECD
#undef COMPUTEF64
#undef WAITV4
#undef WAITV0

    // ---- single deferred epilogue: scales + t1 + rowfd + rowrc ----
    // C/D layout: col = lane&15, row = (lane>>4)*4 + reg (dtype-independent)
    float scc_[4], sfc_[4];
    #pragma unroll
    for (int q = 0; q < 4; q++) {
        size_t colp = (size_t)NPTP + (size_t)n * PPAD + bp2 + wn*64 + q*16 + frow;
        scc_[q] = sC[colp];
        sfc_[q] = sF[colp];
    }

    float t1 = 0.f;
    #pragma unroll
    for (int m = 0; m < 4; m++) {
        #pragma unroll
        for (int r = 0; r < 4; r++) {
            size_t rowp = (size_t)n * PPAD + bp1 + wm*64 + m*16 + fcg*4 + r;
            float scr = sC[rowp];
            float sfr = sF[rowp];
            float sf = 0.f, sr = 0.f;
            #pragma unroll
            for (int q = 0; q < 4; q++) {
                float fdv = accfd[m][q][r] * sfr * sfc_[q];
                float rcv = bup(pcd[m][q][r >> 1], r & 1) * scr * scc_[q];
                t1 += rcv * fdv;
                sf += fdv;
                sr += rcv;
            }
            #pragma unroll
            for (int d = 1; d < 16; d <<= 1) {
                sf += __shfl_xor(sf, d, 64);
                sr += __shfl_xor(sr, d, 64);
            }
            if ((lane & 15) == 0) {
                int row = bp1 + wm*64 + m*16 + fcg*4 + r;
                atomicAdd(&rowfd[n * PPAD + row], sf);
                atomicAdd(&rowrc[n * PPAD + row], sr);
            }
        }
    }
    #pragma unroll
    for (int d = 1; d < 64; d <<= 1) t1 += __shfl_xor(t1, d, 64);
    __shared__ float t1s[4];
    if (lane == 0) t1s[wv] = t1;
    __syncthreads();
    if (t == 0) atomicAdd(t1out, t1s[0] + t1s[1] + t1s[2] + t1s[3]);
}

// ---------------------------------------------------------------------------
// Kernel 4: finalize. loss = -(T1 - cross/PP + (Sfd/M)*Src)/M
// ---------------------------------------------------------------------------
__global__ __launch_bounds__(1024) void k_final(
    const float* __restrict__ rowfd, const float* __restrict__ rowrc,
    const float* __restrict__ t1p, float* __restrict__ out)
{
    const int t = threadIdx.x;
    double cr = 0.0, sf = 0.0, sr = 0.0;
    for (int i = t; i < NN * PPAD; i += 1024) {
        double a = rowfd[i], b = rowrc[i];
        cr += a * b; sf += a; sr += b;
    }
    __shared__ double sh[1024];
    sh[t] = cr; __syncthreads();
    for (int s = 512; s > 0; s >>= 1) { if (t < s) sh[t] += sh[t + s]; __syncthreads(); }
    cr = sh[0]; __syncthreads();
    sh[t] = sf; __syncthreads();
    for (int s = 512; s > 0; s >>= 1) { if (t < s) sh[t] += sh[t + s]; __syncthreads(); }
    sf = sh[0]; __syncthreads();
    sh[t] = sr; __syncthreads();
    for (int s = 512; s > 0; s >>= 1) { if (t < s) sh[t] += sh[t + s]; __syncthreads(); }
    sr = sh[0];
    if (t == 0) {
        double M = (double)NN * (double)PP * (double)PP;
        double t1 = (double)t1p[0];
        double bracket = t1 - cr / (double)PP + (sf / M) * sr;
        out[0] = (float)(-bracket / M);
    }
}

// ---------------------------------------------------------------------------
extern "C" void kernel_launch(void* const* d_in, const int* in_sizes, int n_in,
                              void* d_out, int out_size, void* d_ws, size_t ws_size,
                              hipStream_t stream)
{
    const float* orig_feats     = (const float*)d_in[0];
    const float* orig_feats_pos = (const float*)d_in[1];
    const float* orig_code      = (const float*)d_in[2];
    const float* orig_code_pos  = (const float*)d_in[3];
    const float* coords1        = (const float*)d_in[4];
    const float* coords2        = (const float*)d_in[5];

    // ---- workspace layout ----
    char* ws = (char*)d_ws;
    float* t1    = (float*)(ws + 0);                      //      256 B
    float* rowfd = (float*)(ws + 256);                    //  106,496 B (NN*PPAD)
    float* rowrc = (float*)(ws + 106752);                 //  106,496 B
    float* nrmF  = (float*)(ws + 213248);                 //  212,992 B (2*NPTP)
    float* nrmC  = (float*)(ws + 426240);                 //  212,992 B
    const size_t zeroBytes = 639232;                      // t1+rowsums+nrms
    float* sclF  = (float*)(ws + 639232);                 //  212,992 B
    float* sclC  = (float*)(ws + 852224);                 //  212,992 B
    unsigned char* OF0 = (unsigned char*)(ws + 1065216);  // [16][24][4][1664][8B] fp8
    unsigned char* OF1 = OF0 + 20447232ull;
    short* OC0 = (short*)(OF1 + 20447232ull);             // [16][2][1664][32] bf16
    short* OC1 = (short*)((char*)OC0 + 3407872ull);

    (void)hipMemsetAsync(d_ws, 0, zeroBytes, stream);   // t1/rowsums/nrms

    k_sample<<<dim3(3328), 256, 0, stream>>>(
        orig_feats, orig_feats_pos, orig_code, orig_code_pos,
        coords1, coords2, nrmF, nrmC, OF0, OF1, OC0, OC1);

    k_nrm<<<dim3((2*NPTP + 255)/256, 2), 256, 0, stream>>>(
        nrmF, nrmC, sclF, sclC);

    k_corr<<<dim3(2704), 256, 0, stream>>>(
        OF0, OF1, OC0, OC1, sclF, sclC, rowfd, rowrc, t1);

    k_final<<<1, 1024, 0, stream>>>(rowfd, rowrc, t1, (float*)d_out);
}

// Round 13
// 205.154 us; speedup vs baseline: 1.3113x; 1.0308x over previous
//
#include <hip/hip_runtime.h>
#include <hip/hip_bf16.h>

// Problem constants
#define NN 16
#define CF 768
#define CC 64
#define HH 56
#define WW 56
#define SS 40
#define PP (SS*SS)          // 1600 positions per image
#define PPAD 1664           // padded to 13*128 for 128-tile GEMM
#define NPT (NN*PP)         // 25600
#define NPTP (NN*PPAD)      // 26624
#define HWP (HH*WW)         // 3136

typedef __attribute__((ext_vector_type(8))) short short8;
typedef __attribute__((ext_vector_type(4))) float f32x4;

typedef const __attribute__((address_space(1))) void* gas_p;
typedef __attribute__((address_space(3))) void* las_p;

__device__ __forceinline__ unsigned f2b(float f) {
    __hip_bfloat16 b = __float2bfloat16(f);
    return (unsigned)*(unsigned short*)&b;
}
__device__ __forceinline__ float bup(unsigned u, int hi) {
    unsigned bits = hi ? (u & 0xffff0000u) : (u << 16);
    return __uint_as_float(bits);
}

// Shared bilinear helper — EXACT same arithmetic as validated round-1 kernel.
__device__ __forceinline__ void bilin(float gx, float gy,
    int& o00, int& o01, int& o10, int& o11,
    float& w00, float& w01, float& w10, float& w11)
{
    float x = (gx + 1.f) * 0.5f * (float)(WW - 1);
    float y = (gy + 1.f) * 0.5f * (float)(HH - 1);
    x = fminf(fmaxf(x, 0.f), (float)(WW - 1));
    y = fminf(fmaxf(y, 0.f), (float)(HH - 1));
    float xf = floorf(x), yf = floorf(y);
    int x0 = (int)xf, y0 = (int)yf;
    int x1 = min(x0 + 1, WW - 1), y1 = min(y0 + 1, HH - 1);
    float wx = x - xf, wy = y - yf;
    w00 = (1.f-wx)*(1.f-wy); w01 = wx*(1.f-wy); w10 = (1.f-wx)*wy; w11 = wx*wy;
    o00 = y0*WW + x0; o01 = y0*WW + x1; o10 = y1*WW + x0; o11 = y1*WW + x1;
}

// ---------------------------------------------------------------------------
// Kernel 1: sampling — round-13 change: bilinear gather uses CONSTANT-offset
// paired reads pl[po], pl[po+1], pl[po+56], pl[po+57] (compiler merges into
// 2x ds_read2_b32), replacing 4 runtime-indexed ds_read_b32 + address math.
// Bit-exact: at clamped edges the affected weights are exactly 0, and the
// out-of-row locations hold finite staged data (clamped-source tail writes),
// so 0*finite = 0. With this data (coords in [0,1)) edges never trigger.
// Everything else verbatim round-8/9 (validated 3x): fp8 k-major feats,
// bf16 code, 2x16KB dbuf plane via global_load_lds + counted vmcnt(4).
// ---------------------------------------------------------------------------
__global__ __launch_bounds__(256) void k_sample(
    const float* __restrict__ f0, const float* __restrict__ f1,
    const float* __restrict__ c0in, const float* __restrict__ c1in,
    const float* __restrict__ g0, const float* __restrict__ g1,
    float* __restrict__ nrmF, float* __restrict__ nrmC,
    unsigned char* __restrict__ OF0, unsigned char* __restrict__ OF1,
    short* __restrict__ OC0, short* __restrict__ OC1)
{
    // decode quarter-interleaved flat index (identical to validated kernel)
    const int flat = blockIdx.x;                       // [0, 3328)
    const int q    = (flat >> 3) & 3;                  // quarter
    const int u    = ((flat >> 5) << 3) | (flat & 7);  // [0, 832)
    const int set  = u / 416;                          // 26*16 = 416
    const int rem  = u % 416;
    const int n    = rem / 26;
    const int v    = rem % 26;                         // 0..23 feats, 24..25 code
    const bool isF = v < 24;
    const int ks   = isF ? v : v - 24;
    const int g    = ks * 4 + q;                       // 8-channel group index

    const float* src0; float* nrm;
    if (isF) {
        src0 = (set ? f1 : f0) + ((size_t)n * CF + g * 8) * HWP;
        nrm  = nrmF + (size_t)set * NPTP;
    } else {
        src0 = (set ? c1in : c0in) + ((size_t)n * CC + g * 8) * HWP;
        nrm  = nrmC + (size_t)set * NPTP;
    }
    unsigned char* outF = set ? OF1 : OF0;
    short*         outC = set ? OC1 : OC0;
    const float* gr = set ? g1 : g0;
    const int t = threadIdx.x;

    __shared__ float plane[2][4096];   // 2 x 16 KB double buffer (784 f4 used)

    // ---- per-position bilinear meta, computed once ----
    int   po[7];
    float pw[7][4];
    #pragma unroll
    for (int i = 0; i < 7; i++) {
        int p = t + i * 256;
        if (p < PP) {
            float2 gg = *(const float2*)&gr[2 * (n * PP + p)];
            int o00, o01, o10, o11; float w00, w01, w10, w11;
            bilin(gg.x*2.f - 1.f, gg.y*2.f - 1.f, o00, o01, o10, o11, w00, w01, w10, w11);
            po[i] = o00;
            pw[i][0] = w00; pw[i][1] = w01; pw[i][2] = w10; pw[i][3] = w11;
        } else {
            po[i] = 0;
            pw[i][0] = pw[i][1] = pw[i][2] = pw[i][3] = 0.f;   // pad -> exact 0
        }
    }

    auto* pl3 = (__attribute__((address_space(3))) char*)&plane[0][0];

#define ISSUE(C)                                                                    \
    do {                                                                            \
        const char* sp_ = (const char*)(src0 + (C) * HWP);                          \
        _Pragma("unroll")                                                           \
        for (int i_ = 0; i_ < 4; i_++) {                                            \
            int j_  = t + i_ * 256;                                                 \
            int jc_ = min(j_, 783);                                                 \
            __builtin_amdgcn_global_load_lds((gas_p)(sp_ + jc_ * 16),               \
                (las_p)(pl3 + (((C) & 1) * 16384 + j_ * 16)), 16, 0, 0);            \
        }                                                                           \
    } while (0)

    float ss[7];
    float fv[7][8];     // per-position channel values (indices all constant)
    #pragma unroll
    for (int i = 0; i < 7; i++) ss[i] = 0.f;

    ISSUE(0);
    #pragma unroll
    for (int c = 0; c < 8; c++) {
        if (c < 7) {
            ISSUE(c + 1);
            asm volatile("s_waitcnt vmcnt(4)" ::: "memory");   // my ch-c loads done
        } else {
            asm volatile("s_waitcnt vmcnt(0)" ::: "memory");
        }
        __builtin_amdgcn_sched_barrier(0);
        __builtin_amdgcn_s_barrier();              // all waves' ch-c loads done
        const float* pl = &plane[c & 1][0];
        #pragma unroll
        for (int i = 0; i < 7; i++) {
            // constant-offset pairs -> 2x ds_read2_b32 (offsets {0,1},{56,57})
            float a0 = pl[po[i]];
            float a1 = pl[po[i] + 1];
            float b0 = pl[po[i] + WW];
            float b1 = pl[po[i] + WW + 1];
            float val = pw[i][0]*a0 + pw[i][1]*a1 + pw[i][2]*b0 + pw[i][3]*b1;
            ss[i] += val * val;
            fv[i][c] = val;
        }
        __builtin_amdgcn_sched_barrier(0);
        __builtin_amdgcn_s_barrier();              // compute done before reuse
    }
#undef ISSUE

    if (isF) {
        // k-major fp8 layout: [n][24][q=4][p][8 B]; this block owns kchunk q
        const size_t ob = ((size_t)((n * 24 + ks) * 4 + q)) * PPAD * 8;
        #pragma unroll
        for (int i = 0; i < 7; i++) {
            int p = t + i * 256;
            if (p < PPAD) {
                unsigned w0 = 0u, w1 = 0u;
                w0 = __builtin_amdgcn_cvt_pk_fp8_f32(fv[i][0], fv[i][1], w0, 0);
                w0 = __builtin_amdgcn_cvt_pk_fp8_f32(fv[i][2], fv[i][3], w0, 1);
                w1 = __builtin_amdgcn_cvt_pk_fp8_f32(fv[i][4], fv[i][5], w1, 0);
                w1 = __builtin_amdgcn_cvt_pk_fp8_f32(fv[i][6], fv[i][7], w1, 1);
                uint2 w; w.x = w0; w.y = w1;
                *(uint2*)&outF[ob + (size_t)p * 8] = w;
                if (p < PP) atomicAdd(&nrm[n * PPAD + p], ss[i]);
            }
        }
    } else {
        // [n][2][p][32 shorts] bf16 layout (unchanged)
        const size_t ob = ((size_t)(n * 2 + ks)) * PPAD * 32 + q * 8;
        #pragma unroll
        for (int i = 0; i < 7; i++) {
            int p = t + i * 256;
            if (p < PPAD) {
                short ov[8] __attribute__((aligned(16)));
                #pragma unroll
                for (int c = 0; c < 8; c++) {
                    __hip_bfloat16 b = __float2bfloat16(fv[i][c]);
                    ov[c] = *(short*)&b;
                }
                *(short8*)&outC[ob + (size_t)p * 32] = *(const short8*)ov;
                if (p < PP) atomicAdd(&nrm[n * PPAD + p], ss[i]);
            }
        }
    }
}

// ---------------------------------------------------------------------------
// Kernel 2: nrm -> scale (validated round 10). Pad rows -> scale 0.
// ---------------------------------------------------------------------------
__global__ __launch_bounds__(256) void k_nrm(
    const float* __restrict__ nrmF, const float* __restrict__ nrmC,
    float* __restrict__ sclF, float* __restrict__ sclC)
{
    const int i = blockIdx.x * 256 + threadIdx.x;    // [0, 2*NPTP)
    if (i >= 2 * NPTP) return;
    const float* nrm = blockIdx.y ? nrmC : nrmF;
    float*       scl = blockIdx.y ? sclC : sclF;
    const int p = i % PPAD;
    float s = (p < PP) ? 1.f / fmaxf(sqrtf(nrm[i]), 1e-10f) : 0.f;
    scl[i] = s;
}

// ---------------------------------------------------------------------------
// Kernel 3: fused dual correlation GEMM — VERBATIM round-9/12 (validated
// best, k_corr ~122us): fp8 k-major fd with BK=64 slots (12 fd + 2 cd),
// 3-buffer counted-vmcnt pipeline, conflict-free k-major LDS reads, bf16 cd
// prologue with deferred pcd pack, XCD-chunked swizzle, 84 VGPR, 3 blocks/CU.
// ---------------------------------------------------------------------------
__global__ __launch_bounds__(256, 3) void k_corr(
    const unsigned char* __restrict__ A, const unsigned char* __restrict__ B,
    const short* __restrict__ C, const short* __restrict__ D,
    const float* __restrict__ sF, const float* __restrict__ sC,
    float* __restrict__ rowfd, float* __restrict__ rowrc, float* __restrict__ t1out)
{
    // XCD-chunked swizzle: 2704 blocks = 8 XCDs x 338; x fastest within chunk
    const int flat = blockIdx.x;
    const int v   = (flat & 7) * 338 + (flat >> 3);
    const int n   = v / 169;
    const int rr  = v - n * 169;
    const int bp1 = (rr / 13) * 128;
    const int bp2 = (rr % 13) * 128;

    __shared__ char Asb[3][8192];   // 3 buffers x 8 KB (cd bf16 slab / fd fp8 BK=64 tile)
    __shared__ char Bsb[3][8192];

    const int t    = threadIdx.x;
    const int wv   = t >> 6, lane = t & 63;
    const int wm   = wv >> 1, wn = wv & 1;
    const int frow = lane & 15, fcg = lane >> 4;     // fragment row / k-chunk
    const int fslot = fcg ^ ((frow >> 1) & 3);       // bank-swizzled slot (cd bf16)

    // ---- cd (bf16) staging geometry: chunk g = (wv*2+i)*64 + lane, [0,512)
    const int sg0  = wv * 2 * 64 + lane;
    const int row0 = sg0 >> 2,        cg0 = (sg0 & 3) ^ ((row0 >> 1) & 3);
    const int sg1  = sg0 + 64;
    const int row1 = sg1 >> 2,        cg1 = (sg1 & 3) ^ ((row1 >> 1) & 3);
    const size_t kstep_s = (size_t)PPAD * 32;        // shorts per bf16 BK=32 slab
    const short* cdC = C + (size_t)n * 2 * kstep_s;
    const short* cdD = D + (size_t)n * 2 * kstep_s;
    const size_t toA0 = (size_t)(bp1 + row0) * 32 + cg0 * 8;
    const size_t toA1 = (size_t)(bp1 + row1) * 32 + cg1 * 8;
    const size_t toB0 = (size_t)(bp2 + row0) * 32 + cg0 * 8;
    const size_t toB1 = (size_t)(bp2 + row1) * 32 + cg1 * 8;
    auto* As3s = (__attribute__((address_space(3))) short*)&Asb[0][0];
    auto* Bs3s = (__attribute__((address_space(3))) short*)&Bsb[0][0];
    const short* AsS = (const short*)&Asb[0][0];
    const short* BsS = (const short*)&Bsb[0][0];
    const int ldsA0 = (wv * 2    ) * 512;  // shorts within one 4096-short buffer
    const int ldsA1 = (wv * 2 + 1) * 512;

    // ---- fd (fp8) staging geometry, k-major, BK=64 ----
    // global: [n][24 steps][4][PPAD][8B] = linear kchunks 0..95, kchunk K at
    // byte K*(PPAD*8). BK=64 tile T = kchunks 8T..8T+7, FDTILE bytes apart.
    const size_t FDTILE = (size_t)PPAD * 64;         // BYTES per fp8 BK=64 tile
    const unsigned char* fdA = A + (size_t)n * 24 * ((size_t)PPAD * 32);
    const unsigned char* fdB = B + (size_t)n * 24 * ((size_t)PPAD * 32);
    // wave wv, glds j in {0,1}: fills LDS kchunk (wv*2+j); lane covers rows
    // 2*lane, 2*lane+1 (16B). Global src = kchunk byte base + (bp+2*lane)*8.
    const size_t toAf0 = (size_t)(wv * 2    ) * (PPAD * 8) + (size_t)(bp1 + 2 * lane) * 8;
    const size_t toAf1 = (size_t)(wv * 2 + 1) * (PPAD * 8) + (size_t)(bp1 + 2 * lane) * 8;
    const size_t toBf0 = (size_t)(wv * 2    ) * (PPAD * 8) + (size_t)(bp2 + 2 * lane) * 8;
    const size_t toBf1 = (size_t)(wv * 2 + 1) * (PPAD * 8) + (size_t)(bp2 + 2 * lane) * 8;
    auto* Asb3 = (__attribute__((address_space(3))) char*)&Asb[0][0];
    auto* Bsb3 = (__attribute__((address_space(3))) char*)&Bsb[0][0];
    const int fldsW0 = (wv * 2    ) * 1024;   // wave-uniform byte base (+lane*16)
    const int fldsW1 = (wv * 2 + 1) * 1024;

#define STAGECD(BUF, OFF)                                                           \
    do {                                                                            \
        const size_t off_ = (OFF);                                                  \
        const int b_ = (BUF) * 4096;                                                \
        __builtin_amdgcn_global_load_lds((gas_p)(cdC + toA0 + off_),                \
                                         (las_p)(As3s + b_ + ldsA0), 16, 0, 0);     \
        __builtin_amdgcn_global_load_lds((gas_p)(cdC + toA1 + off_),                \
                                         (las_p)(As3s + b_ + ldsA1), 16, 0, 0);     \
        __builtin_amdgcn_global_load_lds((gas_p)(cdD + toB0 + off_),                \
                                         (las_p)(Bs3s + b_ + ldsA0), 16, 0, 0);     \
        __builtin_amdgcn_global_load_lds((gas_p)(cdD + toB1 + off_),                \
                                         (las_p)(Bs3s + b_ + ldsA1), 16, 0, 0);     \
    } while (0)

// stage one BK=64 fp8 tile (8 KB/operand) into buffer BUF: 4 glds/thread
#define STAGEF(TILE, BUF)                                                           \
    do {                                                                            \
        const size_t off_ = (size_t)(TILE) * FDTILE;                                \
        __builtin_amdgcn_global_load_lds((gas_p)(fdA + toAf0 + off_),               \
                                         (las_p)(Asb3 + (BUF) * 8192 + fldsW0), 16, 0, 0); \
        __builtin_amdgcn_global_load_lds((gas_p)(fdA + toAf1 + off_),               \
                                         (las_p)(Asb3 + (BUF) * 8192 + fldsW1), 16, 0, 0); \
        __builtin_amdgcn_global_load_lds((gas_p)(fdB + toBf0 + off_),               \
                                         (las_p)(Bsb3 + (BUF) * 8192 + fldsW0), 16, 0, 0); \
        __builtin_amdgcn_global_load_lds((gas_p)(fdB + toBf1 + off_),               \
                                         (las_p)(Bsb3 + (BUF) * 8192 + fldsW1), 16, 0, 0); \
    } while (0)

#define COMPUTECD(BUF, ACC)                                                         \
    do {                                                                            \
        short8 af[4], bf[4];                                                        \
        _Pragma("unroll")                                                           \
        for (int m = 0; m < 4; m++)                                                 \
            af[m] = *(const short8*)&AsS[(BUF)*4096 + (wm*64 + m*16 + frow)*32 + fslot*8]; \
        _Pragma("unroll")                                                           \
        for (int q = 0; q < 4; q++)                                                 \
            bf[q] = *(const short8*)&BsS[(BUF)*4096 + (wn*64 + q*16 + frow)*32 + fslot*8]; \
        _Pragma("unroll")                                                           \
        for (int m = 0; m < 4; m++)                                                 \
            _Pragma("unroll")                                                       \
            for (int q = 0; q < 4; q++)                                             \
                ACC[m][q] = __builtin_amdgcn_mfma_f32_16x16x32_bf16(af[m], bf[q], ACC[m][q], 0, 0, 0); \
    } while (0)

// BK=64 fp8 compute: 2 K-substeps; LDS kchunk = kk*4 + fcg; quarter-wave
// reads 16 consecutive 8B granules (all 32 banks once) — conflict-free.
#define COMPUTEF64(BUF, ACC)                                                        \
    do {                                                                            \
        _Pragma("unroll")                                                           \
        for (int kk_ = 0; kk_ < 2; kk_++) {                                         \
            long af[4], bf[4];                                                      \
            const int kb_ = (BUF) * 8192 + (kk_ * 4 + fcg) * 1024;                  \
            _Pragma("unroll")                                                       \
            for (int m = 0; m < 4; m++)                                             \
                af[m] = *(const long*)&Asb[0][kb_ + (wm*64 + m*16 + frow)*8];       \
            _Pragma("unroll")                                                       \
            for (int q = 0; q < 4; q++)                                             \
                bf[q] = *(const long*)&Bsb[0][kb_ + (wn*64 + q*16 + frow)*8];       \
            _Pragma("unroll")                                                       \
            for (int m = 0; m < 4; m++)                                             \
                _Pragma("unroll")                                                   \
                for (int q = 0; q < 4; q++)                                         \
                    ACC[m][q] = __builtin_amdgcn_mfma_f32_16x16x32_fp8_fp8(af[m], bf[q], ACC[m][q], 0, 0, 0); \
        }                                                                           \
    } while (0)

#define WAITV4  do { asm volatile("s_waitcnt vmcnt(4)" ::: "memory");               \
                     __builtin_amdgcn_sched_barrier(0);                             \
                     __builtin_amdgcn_s_barrier(); } while (0)
#define WAITV0  do { asm volatile("s_waitcnt vmcnt(0)" ::: "memory");               \
                     __builtin_amdgcn_sched_barrier(0);                             \
                     __builtin_amdgcn_s_barrier(); } while (0)

    unsigned pcd[4][4][2];   // raw relu(cd) packed as bf16 pairs (32 VGPR)

    // ---- prologue: stage cd steps 0,1 (4 glds each) ----
    STAGECD(0, 0);
    STAGECD(1, kstep_s);

    // ---- cd slots 0,1 ----
    {
        f32x4 acccd[4][4];
        #pragma unroll
        for (int m = 0; m < 4; m++)
            #pragma unroll
            for (int q = 0; q < 4; q++)
                #pragma unroll
                for (int r = 0; r < 4; r++) acccd[m][q][r] = 0.f;

        WAITV4;                         // cd0 landed (cd1's 4 in flight)
        STAGEF(0, 2);                   // fd tile 0 -> buf2 (+4)
        COMPUTECD(0, acccd);
        WAITV4;                         // cd1 landed (fd0's 4 in flight)
        STAGEF(1, 0);                   // fd tile 1 -> buf0 (+4)
        COMPUTECD(1, acccd);

        // pack raw relu(cd) -> bf16 pairs (pure VALU; scales deferred)
        #pragma unroll
        for (int m = 0; m < 4; m++)
            #pragma unroll
            for (int q = 0; q < 4; q++) {
                float r0 = fmaxf(acccd[m][q][0], 0.f);
                float r1 = fmaxf(acccd[m][q][1], 0.f);
                float r2 = fmaxf(acccd[m][q][2], 0.f);
                float r3 = fmaxf(acccd[m][q][3], 0.f);
                pcd[m][q][0] = f2b(r0) | (f2b(r1) << 16);
                pcd[m][q][1] = f2b(r2) | (f2b(r3) << 16);
            }
    }   // acccd dies (AGPRs freed before accfd)

    // ---- fd slots: 12 BK=64 tiles, tile j in buf (2+j)%3, stage 2-ahead ----
    f32x4 accfd[4][4];
    #pragma unroll
    for (int m = 0; m < 4; m++)
        #pragma unroll
        for (int q = 0; q < 4; q++)
            #pragma unroll
            for (int r = 0; r < 4; r++) accfd[m][q][r] = 0.f;

    for (int kp = 0; kp < 4; kp++) {
        const int tb = 3 * kp;
        // slot: compute tile 3kp (buf2), stage tile 3kp+2 -> buf1
        WAITV4;
        STAGEF(tb + 2, 1);
        COMPUTEF64(2, accfd);
        // slot: compute tile 3kp+1 (buf0), stage tile 3kp+3 -> buf2
        WAITV4;
        if (kp < 3) STAGEF(tb + 3, 2);
        COMPUTEF64(0, accfd);
        // slot: compute tile 3kp+2 (buf1), stage tile 3kp+4 -> buf0
        if (kp < 3) {
            WAITV4;
            STAGEF(tb + 4, 0);
        } else {
            WAITV0;
        }
        COMPUTEF64(1, accfd);
    }
#undef STAGECD
#undef STAGEF
#undef COMPUTECD
#undef COMPUTEF64
#undef WAITV4
#undef WAITV0

    // ---- single deferred epilogue: scales + t1 + rowfd + rowrc ----
    // C/D layout: col = lane&15, row = (lane>>4)*4 + reg (dtype-independent)
    float scc_[4], sfc_[4];
    #pragma unroll
    for (int q = 0; q < 4; q++) {
        size_t colp = (size_t)NPTP + (size_t)n * PPAD + bp2 + wn*64 + q*16 + frow;
        scc_[q] = sC[colp];
        sfc_[q] = sF[colp];
    }

    float t1 = 0.f;
    #pragma unroll
    for (int m = 0; m < 4; m++) {
        #pragma unroll
        for (int r = 0; r < 4; r++) {
            size_t rowp = (size_t)n * PPAD + bp1 + wm*64 + m*16 + fcg*4 + r;
            float scr = sC[rowp];
            float sfr = sF[rowp];
            float sf = 0.f, sr = 0.f;
            #pragma unroll
            for (int q = 0; q < 4; q++) {
                float fdv = accfd[m][q][r] * sfr * sfc_[q];
                float rcv = bup(pcd[m][q][r >> 1], r & 1) * scr * scc_[q];
                t1 += rcv * fdv;
                sf += fdv;
                sr += rcv;
            }
            #pragma unroll
            for (int d = 1; d < 16; d <<= 1) {
                sf += __shfl_xor(sf, d, 64);
                sr += __shfl_xor(sr, d, 64);
            }
            if ((lane & 15) == 0) {
                int row = bp1 + wm*64 + m*16 + fcg*4 + r;
                atomicAdd(&rowfd[n * PPAD + row], sf);
                atomicAdd(&rowrc[n * PPAD + row], sr);
            }
        }
    }
    #pragma unroll
    for (int d = 1; d < 64; d <<= 1) t1 += __shfl_xor(t1, d, 64);
    __shared__ float t1s[4];
    if (lane == 0) t1s[wv] = t1;
    __syncthreads();
    if (t == 0) atomicAdd(t1out, t1s[0] + t1s[1] + t1s[2] + t1s[3]);
}

// ---------------------------------------------------------------------------
// Kernel 4: finalize. loss = -(T1 - cross/PP + (Sfd/M)*Src)/M
// ---------------------------------------------------------------------------
__global__ __launch_bounds__(1024) void k_final(
    const float* __restrict__ rowfd, const float* __restrict__ rowrc,
    const float* __restrict__ t1p, float* __restrict__ out)
{
    const int t = threadIdx.x;
    double cr = 0.0, sf = 0.0, sr = 0.0;
    for (int i = t; i < NN * PPAD; i += 1024) {
        double a = rowfd[i], b = rowrc[i];
        cr += a * b; sf += a; sr += b;
    }
    __shared__ double sh[1024];
    sh[t] = cr; __syncthreads();
    for (int s = 512; s > 0; s >>= 1) { if (t < s) sh[t] += sh[t + s]; __syncthreads(); }
    cr = sh[0]; __syncthreads();
    sh[t] = sf; __syncthreads();
    for (int s = 512; s > 0; s >>= 1) { if (t < s) sh[t] += sh[t + s]; __syncthreads(); }
    sf = sh[0]; __syncthreads();
    sh[t] = sr; __syncthreads();
    for (int s = 512; s > 0; s >>= 1) { if (t < s) sh[t] += sh[t + s]; __syncthreads(); }
    sr = sh[0];
    if (t == 0) {
        double M = (double)NN * (double)PP * (double)PP;
        double t1 = (double)t1p[0];
        double bracket = t1 - cr / (double)PP + (sf / M) * sr;
        out[0] = (float)(-bracket / M);
    }
}

// ---------------------------------------------------------------------------
extern "C" void kernel_launch(void* const* d_in, const int* in_sizes, int n_in,
                              void* d_out, int out_size, void* d_ws, size_t ws_size,
                              hipStream_t stream)
{
    const float* orig_feats     = (const float*)d_in[0];
    const float* orig_feats_pos = (const float*)d_in[1];
    const float* orig_code      = (const float*)d_in[2];
    const float* orig_code_pos  = (const float*)d_in[3];
    const float* coords1        = (const float*)d_in[4];
    const float* coords2        = (const float*)d_in[5];

    // ---- workspace layout ----
    char* ws = (char*)d_ws;
    float* t1    = (float*)(ws + 0);                      //      256 B
    float* rowfd = (float*)(ws + 256);                    //  106,496 B (NN*PPAD)
    float* rowrc = (float*)(ws + 106752);                 //  106,496 B
    float* nrmF  = (float*)(ws + 213248);                 //  212,992 B (2*NPTP)
    float* nrmC  = (float*)(ws + 426240);                 //  212,992 B
    const size_t zeroBytes = 639232;                      // t1+rowsums+nrms
    float* sclF  = (float*)(ws + 639232);                 //  212,992 B
    float* sclC  = (float*)(ws + 852224);                 //  212,992 B
    unsigned char* OF0 = (unsigned char*)(ws + 1065216);  // [16][24][4][1664][8B] fp8
    unsigned char* OF1 = OF0 + 20447232ull;
    short* OC0 = (short*)(OF1 + 20447232ull);             // [16][2][1664][32] bf16
    short* OC1 = (short*)((char*)OC0 + 3407872ull);

    (void)hipMemsetAsync(d_ws, 0, zeroBytes, stream);   // t1/rowsums/nrms

    k_sample<<<dim3(3328), 256, 0, stream>>>(
        orig_feats, orig_feats_pos, orig_code, orig_code_pos,
        coords1, coords2, nrmF, nrmC, OF0, OF1, OC0, OC1);

    k_nrm<<<dim3((2*NPTP + 255)/256, 2), 256, 0, stream>>>(
        nrmF, nrmC, sclF, sclC);

    k_corr<<<dim3(2704), 256, 0, stream>>>(
        OF0, OF1, OC0, OC1, sclF, sclC, rowfd, rowrc, t1);

    k_final<<<1, 1024, 0, stream>>>(rowfd, rowrc, t1, (float*)d_out);
}

// Round 14
// 203.904 us; speedup vs baseline: 1.3193x; 1.0061x over previous
//
#include <hip/hip_runtime.h>
#include <hip/hip_bf16.h>

// Problem constants
#define NN 16
#define CF 768
#define CC 64
#define HH 56
#define WW 56
#define SS 40
#define PP (SS*SS)          // 1600 positions per image
#define PPAD 1664           // padded to 13*128 for 128-tile GEMM
#define NPT (NN*PP)         // 25600
#define NPTP (NN*PPAD)      // 26624
#define HWP (HH*WW)         // 3136

typedef __attribute__((ext_vector_type(8))) short short8;
typedef __attribute__((ext_vector_type(4))) float f32x4;

typedef const __attribute__((address_space(1))) void* gas_p;
typedef __attribute__((address_space(3))) void* las_p;

__device__ __forceinline__ unsigned f2b(float f) {
    __hip_bfloat16 b = __float2bfloat16(f);
    return (unsigned)*(unsigned short*)&b;
}
__device__ __forceinline__ float bup(unsigned u, int hi) {
    unsigned bits = hi ? (u & 0xffff0000u) : (u << 16);
    return __uint_as_float(bits);
}

// Shared bilinear helper — EXACT same arithmetic as validated round-1 kernel.
__device__ __forceinline__ void bilin(float gx, float gy,
    int& o00, int& o01, int& o10, int& o11,
    float& w00, float& w01, float& w10, float& w11)
{
    float x = (gx + 1.f) * 0.5f * (float)(WW - 1);
    float y = (gy + 1.f) * 0.5f * (float)(HH - 1);
    x = fminf(fmaxf(x, 0.f), (float)(WW - 1));
    y = fminf(fmaxf(y, 0.f), (float)(HH - 1));
    float xf = floorf(x), yf = floorf(y);
    int x0 = (int)xf, y0 = (int)yf;
    int x1 = min(x0 + 1, WW - 1), y1 = min(y0 + 1, HH - 1);
    float wx = x - xf, wy = y - yf;
    w00 = (1.f-wx)*(1.f-wy); w01 = wx*(1.f-wy); w10 = (1.f-wx)*wy; w11 = wx*wy;
    o00 = y0*WW + x0; o01 = y0*WW + x1; o10 = y1*WW + x0; o11 = y1*WW + x1;
}

// ---------------------------------------------------------------------------
// Kernel 1: sampling — round 14: 3-buffer plane rotation with 2-deep channel
// prefetch (counted vmcnt(8), the same ledger discipline validated in k_corr):
// the old double-buffer issued c+1 and immediately waited on c (1 phase ~400cy
// of cover vs ~900cy HBM latency — latency-bound, r13 counters). Now channels
// c+1,c+2 stay in flight across two compute phases. Gather uses the r13
// constant-offset paired reads (bit-exact; conflicts are data-dependent and
// unchanged). Outputs/numerics byte-identical to the validated r13 kernel.
// ---------------------------------------------------------------------------
__global__ __launch_bounds__(256) void k_sample(
    const float* __restrict__ f0, const float* __restrict__ f1,
    const float* __restrict__ c0in, const float* __restrict__ c1in,
    const float* __restrict__ g0, const float* __restrict__ g1,
    float* __restrict__ nrmF, float* __restrict__ nrmC,
    unsigned char* __restrict__ OF0, unsigned char* __restrict__ OF1,
    short* __restrict__ OC0, short* __restrict__ OC1)
{
    // decode quarter-interleaved flat index (identical to validated kernel)
    const int flat = blockIdx.x;                       // [0, 3328)
    const int q    = (flat >> 3) & 3;                  // quarter
    const int u    = ((flat >> 5) << 3) | (flat & 7);  // [0, 832)
    const int set  = u / 416;                          // 26*16 = 416
    const int rem  = u % 416;
    const int n    = rem / 26;
    const int v    = rem % 26;                         // 0..23 feats, 24..25 code
    const bool isF = v < 24;
    const int ks   = isF ? v : v - 24;
    const int g    = ks * 4 + q;                       // 8-channel group index

    const float* src0; float* nrm;
    if (isF) {
        src0 = (set ? f1 : f0) + ((size_t)n * CF + g * 8) * HWP;
        nrm  = nrmF + (size_t)set * NPTP;
    } else {
        src0 = (set ? c1in : c0in) + ((size_t)n * CC + g * 8) * HWP;
        nrm  = nrmC + (size_t)set * NPTP;
    }
    unsigned char* outF = set ? OF1 : OF0;
    short*         outC = set ? OC1 : OC0;
    const float* gr = set ? g1 : g0;
    const int t = threadIdx.x;

    __shared__ float plane[3][4096];   // 3 x 16 KB rotation (784 f4 used each)

    // ---- per-position bilinear meta, computed once ----
    int   po[7];
    float pw[7][4];
    #pragma unroll
    for (int i = 0; i < 7; i++) {
        int p = t + i * 256;
        if (p < PP) {
            float2 gg = *(const float2*)&gr[2 * (n * PP + p)];
            int o00, o01, o10, o11; float w00, w01, w10, w11;
            bilin(gg.x*2.f - 1.f, gg.y*2.f - 1.f, o00, o01, o10, o11, w00, w01, w10, w11);
            po[i] = o00;
            pw[i][0] = w00; pw[i][1] = w01; pw[i][2] = w10; pw[i][3] = w11;
        } else {
            po[i] = 0;
            pw[i][0] = pw[i][1] = pw[i][2] = pw[i][3] = 0.f;   // pad -> exact 0
        }
    }

    auto* pl3 = (__attribute__((address_space(3))) char*)&plane[0][0];

#define ISSUE(C)                                                                    \
    do {                                                                            \
        const char* sp_ = (const char*)(src0 + (C) * HWP);                          \
        _Pragma("unroll")                                                           \
        for (int i_ = 0; i_ < 4; i_++) {                                            \
            int j_  = t + i_ * 256;                                                 \
            int jc_ = min(j_, 783);                                                 \
            __builtin_amdgcn_global_load_lds((gas_p)(sp_ + jc_ * 16),               \
                (las_p)(pl3 + (((C) % 3) * 16384 + j_ * 16)), 16, 0, 0);            \
        }                                                                           \
    } while (0)

    float ss[7];
    float fv[7][8];     // per-position channel values (indices all constant)
    #pragma unroll
    for (int i = 0; i < 7; i++) ss[i] = 0.f;

    // ---- prologue: 2 channels in flight ----
    ISSUE(0);
    ISSUE(1);
    #pragma unroll
    for (int c = 0; c < 8; c++) {
        if (c < 6) {
            ISSUE(c + 2);
            // outstanding/thread: {c:4, c+1:4, c+2:4}; release channel c
            asm volatile("s_waitcnt vmcnt(8)" ::: "memory");
        } else if (c == 6) {
            asm volatile("s_waitcnt vmcnt(4)" ::: "memory");   // {6:4, 7:4}
        } else {
            asm volatile("s_waitcnt vmcnt(0)" ::: "memory");
        }
        __builtin_amdgcn_sched_barrier(0);
        __builtin_amdgcn_s_barrier();              // all waves' ch-c loads done
        const float* pl = &plane[c % 3][0];
        #pragma unroll
        for (int i = 0; i < 7; i++) {
            // constant-offset pairs -> 2x ds_read2_b32 (offsets {0,1},{56,57})
            float a0 = pl[po[i]];
            float a1 = pl[po[i] + 1];
            float b0 = pl[po[i] + WW];
            float b1 = pl[po[i] + WW + 1];
            float val = pw[i][0]*a0 + pw[i][1]*a1 + pw[i][2]*b0 + pw[i][3]*b1;
            ss[i] += val * val;
            fv[i][c] = val;
        }
        __builtin_amdgcn_sched_barrier(0);
        __builtin_amdgcn_s_barrier();   // reads of buf c%3 done before ISSUE(c+3)
    }
#undef ISSUE

    if (isF) {
        // k-major fp8 layout: [n][24][q=4][p][8 B]; this block owns kchunk q
        const size_t ob = ((size_t)((n * 24 + ks) * 4 + q)) * PPAD * 8;
        #pragma unroll
        for (int i = 0; i < 7; i++) {
            int p = t + i * 256;
            if (p < PPAD) {
                unsigned w0 = 0u, w1 = 0u;
                w0 = __builtin_amdgcn_cvt_pk_fp8_f32(fv[i][0], fv[i][1], w0, 0);
                w0 = __builtin_amdgcn_cvt_pk_fp8_f32(fv[i][2], fv[i][3], w0, 1);
                w1 = __builtin_amdgcn_cvt_pk_fp8_f32(fv[i][4], fv[i][5], w1, 0);
                w1 = __builtin_amdgcn_cvt_pk_fp8_f32(fv[i][6], fv[i][7], w1, 1);
                uint2 w; w.x = w0; w.y = w1;
                *(uint2*)&outF[ob + (size_t)p * 8] = w;
                if (p < PP) atomicAdd(&nrm[n * PPAD + p], ss[i]);
            }
        }
    } else {
        // [n][2][p][32 shorts] bf16 layout (unchanged)
        const size_t ob = ((size_t)(n * 2 + ks)) * PPAD * 32 + q * 8;
        #pragma unroll
        for (int i = 0; i < 7; i++) {
            int p = t + i * 256;
            if (p < PPAD) {
                short ov[8] __attribute__((aligned(16)));
                #pragma unroll
                for (int c = 0; c < 8; c++) {
                    __hip_bfloat16 b = __float2bfloat16(fv[i][c]);
                    ov[c] = *(short*)&b;
                }
                *(short8*)&outC[ob + (size_t)p * 32] = *(const short8*)ov;
                if (p < PP) atomicAdd(&nrm[n * PPAD + p], ss[i]);
            }
        }
    }
}

// ---------------------------------------------------------------------------
// Kernel 2: nrm -> scale (validated round 10). Pad rows -> scale 0.
// ---------------------------------------------------------------------------
__global__ __launch_bounds__(256) void k_nrm(
    const float* __restrict__ nrmF, const float* __restrict__ nrmC,
    float* __restrict__ sclF, float* __restrict__ sclC)
{
    const int i = blockIdx.x * 256 + threadIdx.x;    // [0, 2*NPTP)
    if (i >= 2 * NPTP) return;
    const float* nrm = blockIdx.y ? nrmC : nrmF;
    float*       scl = blockIdx.y ? sclC : sclF;
    const int p = i % PPAD;
    float s = (p < PP) ? 1.f / fmaxf(sqrtf(nrm[i]), 1e-10f) : 0.f;
    scl[i] = s;
}

// ---------------------------------------------------------------------------
// Kernel 3: fused dual correlation GEMM — VERBATIM round-9/12 (validated
// best, k_corr ~122us): fp8 k-major fd with BK=64 slots (12 fd + 2 cd),
// 3-buffer counted-vmcnt pipeline, conflict-free k-major LDS reads, bf16 cd
// prologue with deferred pcd pack, XCD-chunked swizzle, 84 VGPR, 3 blocks/CU.
// ---------------------------------------------------------------------------
__global__ __launch_bounds__(256, 3) void k_corr(
    const unsigned char* __restrict__ A, const unsigned char* __restrict__ B,
    const short* __restrict__ C, const short* __restrict__ D,
    const float* __restrict__ sF, const float* __restrict__ sC,
    float* __restrict__ rowfd, float* __restrict__ rowrc, float* __restrict__ t1out)
{
    // XCD-chunked swizzle: 2704 blocks = 8 XCDs x 338; x fastest within chunk
    const int flat = blockIdx.x;
    const int v   = (flat & 7) * 338 + (flat >> 3);
    const int n   = v / 169;
    const int rr  = v - n * 169;
    const int bp1 = (rr / 13) * 128;
    const int bp2 = (rr % 13) * 128;

    __shared__ char Asb[3][8192];   // 3 buffers x 8 KB (cd bf16 slab / fd fp8 BK=64 tile)
    __shared__ char Bsb[3][8192];

    const int t    = threadIdx.x;
    const int wv   = t >> 6, lane = t & 63;
    const int wm   = wv >> 1, wn = wv & 1;
    const int frow = lane & 15, fcg = lane >> 4;     // fragment row / k-chunk
    const int fslot = fcg ^ ((frow >> 1) & 3);       // bank-swizzled slot (cd bf16)

    // ---- cd (bf16) staging geometry: chunk g = (wv*2+i)*64 + lane, [0,512)
    const int sg0  = wv * 2 * 64 + lane;
    const int row0 = sg0 >> 2,        cg0 = (sg0 & 3) ^ ((row0 >> 1) & 3);
    const int sg1  = sg0 + 64;
    const int row1 = sg1 >> 2,        cg1 = (sg1 & 3) ^ ((row1 >> 1) & 3);
    const size_t kstep_s = (size_t)PPAD * 32;        // shorts per bf16 BK=32 slab
    const short* cdC = C + (size_t)n * 2 * kstep_s;
    const short* cdD = D + (size_t)n * 2 * kstep_s;
    const size_t toA0 = (size_t)(bp1 + row0) * 32 + cg0 * 8;
    const size_t toA1 = (size_t)(bp1 + row1) * 32 + cg1 * 8;
    const size_t toB0 = (size_t)(bp2 + row0) * 32 + cg0 * 8;
    const size_t toB1 = (size_t)(bp2 + row1) * 32 + cg1 * 8;
    auto* As3s = (__attribute__((address_space(3))) short*)&Asb[0][0];
    auto* Bs3s = (__attribute__((address_space(3))) short*)&Bsb[0][0];
    const short* AsS = (const short*)&Asb[0][0];
    const short* BsS = (const short*)&Bsb[0][0];
    const int ldsA0 = (wv * 2    ) * 512;  // shorts within one 4096-short buffer
    const int ldsA1 = (wv * 2 + 1) * 512;

    // ---- fd (fp8) staging geometry, k-major, BK=64 ----
    // global: [n][24 steps][4][PPAD][8B] = linear kchunks 0..95, kchunk K at
    // byte K*(PPAD*8). BK=64 tile T = kchunks 8T..8T+7, FDTILE bytes apart.
    const size_t FDTILE = (size_t)PPAD * 64;         // BYTES per fp8 BK=64 tile
    const unsigned char* fdA = A + (size_t)n * 24 * ((size_t)PPAD * 32);
    const unsigned char* fdB = B + (size_t)n * 24 * ((size_t)PPAD * 32);
    // wave wv, glds j in {0,1}: fills LDS kchunk (wv*2+j); lane covers rows
    // 2*lane, 2*lane+1 (16B). Global src = kchunk byte base + (bp+2*lane)*8.
    const size_t toAf0 = (size_t)(wv * 2    ) * (PPAD * 8) + (size_t)(bp1 + 2 * lane) * 8;
    const size_t toAf1 = (size_t)(wv * 2 + 1) * (PPAD * 8) + (size_t)(bp1 + 2 * lane) * 8;
    const size_t toBf0 = (size_t)(wv * 2    ) * (PPAD * 8) + (size_t)(bp2 + 2 * lane) * 8;
    const size_t toBf1 = (size_t)(wv * 2 + 1) * (PPAD * 8) + (size_t)(bp2 + 2 * lane) * 8;
    auto* Asb3 = (__attribute__((address_space(3))) char*)&Asb[0][0];
    auto* Bsb3 = (__attribute__((address_space(3))) char*)&Bsb[0][0];
    const int fldsW0 = (wv * 2    ) * 1024;   // wave-uniform byte base (+lane*16)
    const int fldsW1 = (wv * 2 + 1) * 1024;

#define STAGECD(BUF, OFF)                                                           \
    do {                                                                            \
        const size_t off_ = (OFF);                                                  \
        const int b_ = (BUF) * 4096;                                                \
        __builtin_amdgcn_global_load_lds((gas_p)(cdC + toA0 + off_),                \
                                         (las_p)(As3s + b_ + ldsA0), 16, 0, 0);     \
        __builtin_amdgcn_global_load_lds((gas_p)(cdC + toA1 + off_),                \
                                         (las_p)(As3s + b_ + ldsA1), 16, 0, 0);     \
        __builtin_amdgcn_global_load_lds((gas_p)(cdD + toB0 + off_),                \
                                         (las_p)(Bs3s + b_ + ldsA0), 16, 0, 0);     \
        __builtin_amdgcn_global_load_lds((gas_p)(cdD + toB1 + off_),                \
                                         (las_p)(Bs3s + b_ + ldsA1), 16, 0, 0);     \
    } while (0)

// stage one BK=64 fp8 tile (8 KB/operand) into buffer BUF: 4 glds/thread
#define STAGEF(TILE, BUF)                                                           \
    do {                                                                            \
        const size_t off_ = (size_t)(TILE) * FDTILE;                                \
        __builtin_amdgcn_global_load_lds((gas_p)(fdA + toAf0 + off_),               \
                                         (las_p)(Asb3 + (BUF) * 8192 + fldsW0), 16, 0, 0); \
        __builtin_amdgcn_global_load_lds((gas_p)(fdA + toAf1 + off_),               \
                                         (las_p)(Asb3 + (BUF) * 8192 + fldsW1), 16, 0, 0); \
        __builtin_amdgcn_global_load_lds((gas_p)(fdB + toBf0 + off_),               \
                                         (las_p)(Bsb3 + (BUF) * 8192 + fldsW0), 16, 0, 0); \
        __builtin_amdgcn_global_load_lds((gas_p)(fdB + toBf1 + off_),               \
                                         (las_p)(Bsb3 + (BUF) * 8192 + fldsW1), 16, 0, 0); \
    } while (0)

#define COMPUTECD(BUF, ACC)                                                         \
    do {                                                                            \
        short8 af[4], bf[4];                                                        \
        _Pragma("unroll")                                                           \
        for (int m = 0; m < 4; m++)                                                 \
            af[m] = *(const short8*)&AsS[(BUF)*4096 + (wm*64 + m*16 + frow)*32 + fslot*8]; \
        _Pragma("unroll")                                                           \
        for (int q = 0; q < 4; q++)                                                 \
            bf[q] = *(const short8*)&BsS[(BUF)*4096 + (wn*64 + q*16 + frow)*32 + fslot*8]; \
        _Pragma("unroll")                                                           \
        for (int m = 0; m < 4; m++)                                                 \
            _Pragma("unroll")                                                       \
            for (int q = 0; q < 4; q++)                                             \
                ACC[m][q] = __builtin_amdgcn_mfma_f32_16x16x32_bf16(af[m], bf[q], ACC[m][q], 0, 0, 0); \
    } while (0)

// BK=64 fp8 compute: 2 K-substeps; LDS kchunk = kk*4 + fcg; quarter-wave
// reads 16 consecutive 8B granules (all 32 banks once) — conflict-free.
#define COMPUTEF64(BUF, ACC)                                                        \
    do {                                                                            \
        _Pragma("unroll")                                                           \
        for (int kk_ = 0; kk_ < 2; kk_++) {                                         \
            long af[4], bf[4];                                                      \
            const int kb_ = (BUF) * 8192 + (kk_ * 4 + fcg) * 1024;                  \
            _Pragma("unroll")                                                       \
            for (int m = 0; m < 4; m++)                                             \
                af[m] = *(const long*)&Asb[0][kb_ + (wm*64 + m*16 + frow)*8];       \
            _Pragma("unroll")                                                       \
            for (int q = 0; q < 4; q++)                                             \
                bf[q] = *(const long*)&Bsb[0][kb_ + (wn*64 + q*16 + frow)*8];       \
            _Pragma("unroll")                                                       \
            for (int m = 0; m < 4; m++)                                             \
                _Pragma("unroll")                                                   \
                for (int q = 0; q < 4; q++)                                         \
                    ACC[m][q] = __builtin_amdgcn_mfma_f32_16x16x32_fp8_fp8(af[m], bf[q], ACC[m][q], 0, 0, 0); \
        }                                                                           \
    } while (0)

#define WAITV4  do { asm volatile("s_waitcnt vmcnt(4)" ::: "memory");               \
                     __builtin_amdgcn_sched_barrier(0);                             \
                     __builtin_amdgcn_s_barrier(); } while (0)
#define WAITV0  do { asm volatile("s_waitcnt vmcnt(0)" ::: "memory");               \
                     __builtin_amdgcn_sched_barrier(0);                             \
                     __builtin_amdgcn_s_barrier(); } while (0)

    unsigned pcd[4][4][2];   // raw relu(cd) packed as bf16 pairs (32 VGPR)

    // ---- prologue: stage cd steps 0,1 (4 glds each) ----
    STAGECD(0, 0);
    STAGECD(1, kstep_s);

    // ---- cd slots 0,1 ----
    {
        f32x4 acccd[4][4];
        #pragma unroll
        for (int m = 0; m < 4; m++)
            #pragma unroll
            for (int q = 0; q < 4; q++)
                #pragma unroll
                for (int r = 0; r < 4; r++) acccd[m][q][r] = 0.f;

        WAITV4;                         // cd0 landed (cd1's 4 in flight)
        STAGEF(0, 2);                   // fd tile 0 -> buf2 (+4)
        COMPUTECD(0, acccd);
        WAITV4;                         // cd1 landed (fd0's 4 in flight)
        STAGEF(1, 0);                   // fd tile 1 -> buf0 (+4)
        COMPUTECD(1, acccd);

        // pack raw relu(cd) -> bf16 pairs (pure VALU; scales deferred)
        #pragma unroll
        for (int m = 0; m < 4; m++)
            #pragma unroll
            for (int q = 0; q < 4; q++) {
                float r0 = fmaxf(acccd[m][q][0], 0.f);
                float r1 = fmaxf(acccd[m][q][1], 0.f);
                float r2 = fmaxf(acccd[m][q][2], 0.f);
                float r3 = fmaxf(acccd[m][q][3], 0.f);
                pcd[m][q][0] = f2b(r0) | (f2b(r1) << 16);
                pcd[m][q][1] = f2b(r2) | (f2b(r3) << 16);
            }
    }   // acccd dies (AGPRs freed before accfd)

    // ---- fd slots: 12 BK=64 tiles, tile j in buf (2+j)%3, stage 2-ahead ----
    f32x4 accfd[4][4];
    #pragma unroll
    for (int m = 0; m < 4; m++)
        #pragma unroll
        for (int q = 0; q < 4; q++)
            #pragma unroll
            for (int r = 0; r < 4; r++) accfd[m][q][r] = 0.f;

    for (int kp = 0; kp < 4; kp++) {
        const int tb = 3 * kp;
        // slot: compute tile 3kp (buf2), stage tile 3kp+2 -> buf1
        WAITV4;
        STAGEF(tb + 2, 1);
        COMPUTEF64(2, accfd);
        // slot: compute tile 3kp+1 (buf0), stage tile 3kp+3 -> buf2
        WAITV4;
        if (kp < 3) STAGEF(tb + 3, 2);
        COMPUTEF64(0, accfd);
        // slot: compute tile 3kp+2 (buf1), stage tile 3kp+4 -> buf0
        if (kp < 3) {
            WAITV4;
            STAGEF(tb + 4, 0);
        } else {
            WAITV0;
        }
        COMPUTEF64(1, accfd);
    }
#undef STAGECD
#undef STAGEF
#undef COMPUTECD
#undef COMPUTEF64
#undef WAITV4
#undef WAITV0

    // ---- single deferred epilogue: scales + t1 + rowfd + rowrc ----
    // C/D layout: col = lane&15, row = (lane>>4)*4 + reg (dtype-independent)
    float scc_[4], sfc_[4];
    #pragma unroll
    for (int q = 0; q < 4; q++) {
        size_t colp = (size_t)NPTP + (size_t)n * PPAD + bp2 + wn*64 + q*16 + frow;
        scc_[q] = sC[colp];
        sfc_[q] = sF[colp];
    }

    float t1 = 0.f;
    #pragma unroll
    for (int m = 0; m < 4; m++) {
        #pragma unroll
        for (int r = 0; r < 4; r++) {
            size_t rowp = (size_t)n * PPAD + bp1 + wm*64 + m*16 + fcg*4 + r;
            float scr = sC[rowp];
            float sfr = sF[rowp];
            float sf = 0.f, sr = 0.f;
            #pragma unroll
            for (int q = 0; q < 4; q++) {
                float fdv = accfd[m][q][r] * sfr * sfc_[q];
                float rcv = bup(pcd[m][q][r >> 1], r & 1) * scr * scc_[q];
                t1 += rcv * fdv;
                sf += fdv;
                sr += rcv;
            }
            #pragma unroll
            for (int d = 1; d < 16; d <<= 1) {
                sf += __shfl_xor(sf, d, 64);
                sr += __shfl_xor(sr, d, 64);
            }
            if ((lane & 15) == 0) {
                int row = bp1 + wm*64 + m*16 + fcg*4 + r;
                atomicAdd(&rowfd[n * PPAD + row], sf);
                atomicAdd(&rowrc[n * PPAD + row], sr);
            }
        }
    }
    #pragma unroll
    for (int d = 1; d < 64; d <<= 1) t1 += __shfl_xor(t1, d, 64);
    __shared__ float t1s[4];
    if (lane == 0) t1s[wv] = t1;
    __syncthreads();
    if (t == 0) atomicAdd(t1out, t1s[0] + t1s[1] + t1s[2] + t1s[3]);
}

// ---------------------------------------------------------------------------
// Kernel 4: finalize. loss = -(T1 - cross/PP + (Sfd/M)*Src)/M
// ---------------------------------------------------------------------------
__global__ __launch_bounds__(1024) void k_final(
    const float* __restrict__ rowfd, const float* __restrict__ rowrc,
    const float* __restrict__ t1p, float* __restrict__ out)
{
    const int t = threadIdx.x;
    double cr = 0.0, sf = 0.0, sr = 0.0;
    for (int i = t; i < NN * PPAD; i += 1024) {
        double a = rowfd[i], b = rowrc[i];
        cr += a * b; sf += a; sr += b;
    }
    __shared__ double sh[1024];
    sh[t] = cr; __syncthreads();
    for (int s = 512; s > 0; s >>= 1) { if (t < s) sh[t] += sh[t + s]; __syncthreads(); }
    cr = sh[0]; __syncthreads();
    sh[t] = sf; __syncthreads();
    for (int s = 512; s > 0; s >>= 1) { if (t < s) sh[t] += sh[t + s]; __syncthreads(); }
    sf = sh[0]; __syncthreads();
    sh[t] = sr; __syncthreads();
    for (int s = 512; s > 0; s >>= 1) { if (t < s) sh[t] += sh[t + s]; __syncthreads(); }
    sr = sh[0];
    if (t == 0) {
        double M = (double)NN * (double)PP * (double)PP;
        double t1 = (double)t1p[0];
        double bracket = t1 - cr / (double)PP + (sf / M) * sr;
        out[0] = (float)(-bracket / M);
    }
}

// ---------------------------------------------------------------------------
extern "C" void kernel_launch(void* const* d_in, const int* in_sizes, int n_in,
                              void* d_out, int out_size, void* d_ws, size_t ws_size,
                              hipStream_t stream)
{
    const float* orig_feats     = (const float*)d_in[0];
    const float* orig_feats_pos = (const float*)d_in[1];
    const float* orig_code      = (const float*)d_in[2];
    const float* orig_code_pos  = (const float*)d_in[3];
    const float* coords1        = (const float*)d_in[4];
    const float* coords2        = (const float*)d_in[5];

    // ---- workspace layout ----
    char* ws = (char*)d_ws;
    float* t1    = (float*)(ws + 0);                      //      256 B
    float* rowfd = (float*)(ws + 256);                    //  106,496 B (NN*PPAD)
    float* rowrc = (float*)(ws + 106752);                 //  106,496 B
    float* nrmF  = (float*)(ws + 213248);                 //  212,992 B (2*NPTP)
    float* nrmC  = (float*)(ws + 426240);                 //  212,992 B
    const size_t zeroBytes = 639232;                      // t1+rowsums+nrms
    float* sclF  = (float*)(ws + 639232);                 //  212,992 B
    float* sclC  = (float*)(ws + 852224);                 //  212,992 B
    unsigned char* OF0 = (unsigned char*)(ws + 1065216);  // [16][24][4][1664][8B] fp8
    unsigned char* OF1 = OF0 + 20447232ull;
    short* OC0 = (short*)(OF1 + 20447232ull);             // [16][2][1664][32] bf16
    short* OC1 = (short*)((char*)OC0 + 3407872ull);

    (void)hipMemsetAsync(d_ws, 0, zeroBytes, stream);   // t1/rowsums/nrms

    k_sample<<<dim3(3328), 256, 0, stream>>>(
        orig_feats, orig_feats_pos, orig_code, orig_code_pos,
        coords1, coords2, nrmF, nrmC, OF0, OF1, OC0, OC1);

    k_nrm<<<dim3((2*NPTP + 255)/256, 2), 256, 0, stream>>>(
        nrmF, nrmC, sclF, sclC);

    k_corr<<<dim3(2704), 256, 0, stream>>>(
        OF0, OF1, OC0, OC1, sclF, sclC, rowfd, rowrc, t1);

    k_final<<<1, 1024, 0, stream>>>(rowfd, rowrc, t1, (float*)d_out);
}